// Round 13
// baseline (868.823 us; speedup 1.0000x reference)
//
#include <hip/hip_runtime.h>
#include <math.h>

#define BN_SC 0.9999950000375f
#define P2N   (6.283185307179586f / 126.f)
#define ATT_SCALE 0.35355339059327373f

typedef float v4f __attribute__((ext_vector_type(4)));
typedef short bf16x8 __attribute__((ext_vector_type(8)));
typedef float f32x4 __attribute__((ext_vector_type(4)));
typedef unsigned short u16;

enum { M_LOCAL = 0, M_GABOR = 1, M_BNRELU6 = 2, M_BIASRELU = 3 };

__device__ __forceinline__ u16 f2bf(float f) {
  unsigned u = __float_as_uint(f);
  return (u16)((u + 0x7FFFu + ((u >> 16) & 1u)) >> 16);
}
__device__ __forceinline__ float bf2f(u16 h) {
  return __uint_as_float(((unsigned)h) << 16);
}

// ------------- rpb bias pre-gather: rpbt[h][j*64+i] = rpb[relidx[i*64+j]*8+h] -------------
__global__ __launch_bounds__(256) void rpbprep_k(
    const float* __restrict__ rpb, const int* __restrict__ relidx, float* __restrict__ rpbt)
{
  int idx = blockIdx.x * 256 + threadIdx.x; // 32768
  int h = idx >> 12, r = idx & 4095, j = r >> 6, i = r & 63;
  rpbt[idx] = rpb[relidx[i * 64 + j] * 8 + h];
}

// ---------------- bias add (local branch: b_l1 + b_l2) ----------------
__global__ void bls_k(const float* __restrict__ a, const float* __restrict__ b,
                      float* __restrict__ o)
{ int i = threadIdx.x; o[i] = a[i] + b[i]; }

// -------- weight split: fp32 [nco][64][ntap] -> bf16 hi/lo [co_off+co][NT][64] --------
__global__ __launch_bounds__(256)
void wsplit_k(const float* __restrict__ w, const float* __restrict__ gsc,
              u16* __restrict__ wh, u16* __restrict__ wl,
              int nco, int ntap, int co_off, int tap_off, int NT)
{
  int i = blockIdx.x * 256 + threadIdx.x;
  if (i >= nco * 64 * ntap) return;
  int t = i % ntap, q = i / ntap;
  int cin = q & 63, co = q >> 6;
  float v = w[i];
  if (gsc) v *= gsc[co_off + co] * BN_SC;
  u16 h = f2bf(v);
  u16 l = f2bf(v - bf2f(h));
  int dst = ((co_off + co) * NT + tap_off + t) * 64 + cin;
  wh[dst] = h; wl[dst] = l;
}

// -------- weight split for stride-2 conv, phase-grouped tap order --------
__global__ __launch_bounds__(256)
void wsplit_gc_k(const float* __restrict__ w, u16* __restrict__ wh, u16* __restrict__ wl)
{
  int i = blockIdx.x * 256 + threadIdx.x;   // 64*64*9 = 36864
  if (i >= 36864) return;
  int t = i % 9, q = i / 9;
  int cin = q & 63, co = q >> 6;
  const int POS[9] = {0, 4, 1, 6, 8, 7, 2, 5, 3};  // pos_of_tap
  float v = w[i];
  u16 h = f2bf(v);
  u16 l = f2bf(v - bf2f(h));
  int dst = (co * 9 + POS[t]) * 64 + cin;
  wh[dst] = h; wl[dst] = l;
}

// -------- DFT trig tables, bf16 hi/lo, 4 tables of [128 ch][128 k] --------
__global__ __launch_bounds__(256)
void tprep_k(u16* __restrict__ tb)
{
  int idx = blockIdx.x * 256 + threadIdx.x;   // 65536
  int tab = idx >> 14, r = idx & 16383;
  int ch = r >> 7, k = r & 127;
  float v = 0.f;
  if (tab == 0) {
    int k2 = ch >> 1;
    if (k < 126) {
      int m = (k * k2) % 126;
      float s, c; sincosf(P2N * (float)m, &s, &c);
      v = (ch & 1) ? -s : c;
    }
  } else if (tab == 1) {
    if (ch < 126 && k < 126) { int m = (ch * k) % 126; v = cosf(P2N * (float)m); }
  } else if (tab == 2) {
    if (ch < 126 && k < 126) { int m = (ch * k) % 126; v = sinf(P2N * (float)m); }
  } else {
    int k2 = k >> 1;
    if (ch < 126) {
      float w = (k2 == 0 || k2 == 63) ? 1.f : 2.f;
      int m = (ch * k2) % 126;
      float s, c; sincosf(P2N * (float)m, &s, &c);
      v = (k & 1) ? -w * s : w * c;
    }
  }
  u16 h = f2bf(v), l = f2bf(v - bf2f(h));
  tb[tab * 32768 + r] = h;
  tb[tab * 32768 + 16384 + r] = l;
}

// -------- input split+transpose: fp32 NCHW [8][64][HW][HW] -> bf16 hi/lo NHWC --------
template<int HW>
__global__ __launch_bounds__(256)
void xsplit_k(const float* __restrict__ in, u16* __restrict__ xh, u16* __restrict__ xl)
{
  __shared__ float t[64 * (HW + 1)];
  const int by = blockIdx.x;          // b*HW + y
  const int tid = threadIdx.x;
  const int b = by / HW, y = by - b * HW;
  const float* ip = in + (size_t)b * 64 * HW * HW + (size_t)y * HW;
  for (int e = tid; e < 64 * HW; e += 256) {
    int cin = e / HW, x = e - cin * HW;
    t[cin * (HW + 1) + x] = ip[(size_t)cin * HW * HW + x];
  }
  __syncthreads();
  u16* oh = xh + (size_t)by * HW * 64;
  u16* ol = xl + (size_t)by * HW * 64;
  for (int e = tid; e < 64 * HW; e += 256) {
    int x = e >> 6, cin = e & 63;
    float v = t[cin * (HW + 1) + x];
    u16 h = f2bf(v);
    oh[e] = h;
    ol[e] = f2bf(v - bf2f(h));
  }
}

// -------- fused maxpool(2x2,s1) + stride-2 phase split: 126^2 fp32 -> 4x 63^2 bf16 NHWC --------
__global__ __launch_bounds__(256)
void mpsplit_k(const float* __restrict__ in, u16* __restrict__ ph_h, u16* __restrict__ ph_l)
{
  __shared__ float rm[126 * 65];      // [col][cin], pitch 65: rowmax of 2 input rows
  const int tid = threadIdx.x;
  const int bx = blockIdx.x;          // b*126 + py*63 + u
  const int b = bx / 126, r = bx % 126;
  const int py = r / 63, u = r % 63;
  const bool valid_u = !(py == 1 && u == 62);
  if (valid_u) {
    const int r0 = 2 * u + py;
    const float* ip = in + (size_t)b * 64 * 15876;
    for (int e = tid; e < 64 * 126; e += 256) {
      int cin = e / 126, col = e - cin * 126;
      const float* p = ip + (size_t)cin * 15876 + (size_t)r0 * 126 + col;
      rm[col * 65 + cin] = fmaxf(p[0], p[126]);
    }
  }
  __syncthreads();
  for (int e = tid; e < 8064; e += 256) {   // 2 px * 63 v * 64 cin
    int px = e / 4032;
    int rr = e - px * 4032;
    int v = rr >> 6, cin = rr & 63;
    float val = 0.f;
    if (valid_u && !(px == 1 && v == 62)) {
      int c0 = 2 * v + px;
      val = fmaxf(rm[c0 * 65 + cin], rm[(c0 + 1) * 65 + cin]);
    }
    u16 h = f2bf(val);
    size_t dst = (((size_t)(b * 4 + py * 2 + px) * 63 + u) * 63 + v) * 64 + cin;
    ph_h[dst] = h;
    ph_l[dst] = f2bf(val - bf2f(h));
  }
}

// ================= MFMA conv3x3 (split-bf16, 3-MFMA fp32-accurate) =================
template<int MODE, int NT, int IN_HW, int OUT_HW, int PAD, bool OUTBF>
__global__ __launch_bounds__(256, 3)
void convmf_k(const u16* __restrict__ xh, const u16* __restrict__ xl,
              const u16* __restrict__ wh, const u16* __restrict__ wl,
              const float* __restrict__ ba, const float* __restrict__ bb,
              float* __restrict__ out, u16* __restrict__ oxh, u16* __restrict__ oxl)
{
  __shared__ uint4 lds4[2916];               // 324 * 144 B = 46656
  char* lds = (char*)lds4;
  const int tid = threadIdx.x;
  const int lane = tid & 63;
  const int wv = __builtin_amdgcn_readfirstlane(tid >> 6);
  const int wco = wv & 1, wpx = wv >> 1;
  const int b = blockIdx.y;
  const int oy0 = (blockIdx.x >> 3) * 16, ox0 = (blockIdx.x & 7) * 16;
  const int iy0 = oy0 - PAD, ix0 = ox0 - PAD;
  const int l15 = lane & 15, l4 = lane >> 4;
  const int bboff = l15 * 144 + l4 * 16;
  const int aoff  = l15 * (NT * 64) + l4 * 8;
  const u16* wh0 = wh + wco * 32 * NT * 64 + aoff;
  const u16* wl0 = wl + wco * 32 * NT * 64 + aoff;

  f32x4 acc[2][8];
#pragma unroll
  for (int f = 0; f < 2; ++f)
#pragma unroll
    for (int r = 0; r < 8; ++r) { f32x4 z = {0.f, 0.f, 0.f, 0.f}; acc[f][r] = z; }

#pragma unroll 1
  for (int cc = 0; cc < 64; cc += 32) {
    __syncthreads();
    for (int e = tid; e < 2592; e += 256) {
      int pix = e >> 3, part = e & 7;
      int lr = pix / 18, lc = pix - lr * 18;
      int iy = iy0 + lr, ix = ix0 + lc;
      uint4 v = make_uint4(0u, 0u, 0u, 0u);
      if ((unsigned)iy < (unsigned)IN_HW && (unsigned)ix < (unsigned)IN_HW) {
        const u16* s = ((part < 4) ? xh : xl)
            + ((size_t)(b * IN_HW + iy) * IN_HW + ix) * 64 + cc + (part & 3) * 8;
        v = *(const uint4*)s;
      }
      *(uint4*)(lds + pix * 144 + part * 16) = v;
    }
    __syncthreads();

    bf16x8 ah0 = *(const bf16x8*)(wh0 + cc);
    bf16x8 al0 = *(const bf16x8*)(wl0 + cc);
    bf16x8 ah1 = *(const bf16x8*)(wh0 + 16 * NT * 64 + cc);
    bf16x8 al1 = *(const bf16x8*)(wl0 + 16 * NT * 64 + cc);

#pragma unroll 1
    for (int t = 0; t < NT; ++t) {
      int tn = (t + 1 < NT) ? t + 1 : t;
      bf16x8 nh0 = *(const bf16x8*)(wh0 + tn * 64 + cc);
      bf16x8 nl0 = *(const bf16x8*)(wl0 + tn * 64 + cc);
      bf16x8 nh1 = *(const bf16x8*)(wh0 + 16 * NT * 64 + tn * 64 + cc);
      bf16x8 nl1 = *(const bf16x8*)(wl0 + 16 * NT * 64 + tn * 64 + cc);
      int te = (t >= 9) ? 4 : t;            // tap 9 (1x1) = center (1,1)
      int dy = te / 3;
      int dx = te - dy * 3;
      const char* pb = lds + ((wpx * 8 + dy) * 18 + dx) * 144 + bboff;
#pragma unroll
      for (int r = 0; r < 8; ++r) {
        bf16x8 bh = *(const bf16x8*)(pb + r * 2592);
        bf16x8 bl = *(const bf16x8*)(pb + r * 2592 + 64);
        acc[0][r] = __builtin_amdgcn_mfma_f32_16x16x32_bf16(ah0, bh, acc[0][r], 0, 0, 0);
        acc[1][r] = __builtin_amdgcn_mfma_f32_16x16x32_bf16(ah1, bh, acc[1][r], 0, 0, 0);
        acc[0][r] = __builtin_amdgcn_mfma_f32_16x16x32_bf16(ah0, bl, acc[0][r], 0, 0, 0);
        acc[0][r] = __builtin_amdgcn_mfma_f32_16x16x32_bf16(al0, bh, acc[0][r], 0, 0, 0);
        acc[1][r] = __builtin_amdgcn_mfma_f32_16x16x32_bf16(ah1, bl, acc[1][r], 0, 0, 0);
        acc[1][r] = __builtin_amdgcn_mfma_f32_16x16x32_bf16(al1, bh, acc[1][r], 0, 0, 0);
      }
      ah0 = nh0; al0 = nl0; ah1 = nh1; al1 = nl1;
    }
  }

  const int ox = ox0 + l15;
#pragma unroll
  for (int f = 0; f < 2; ++f) {
    const int cb = wco * 32 + f * 16 + l4 * 4;
    float bias4[4];
#pragma unroll
    for (int j = 0; j < 4; ++j) {
      int c = cb + j;
      bias4[j] = (MODE == M_GABOR && c >= 32) ? bb[c - 32] : ba[c];
    }
    if (OUTBF) {
#pragma unroll
      for (int r = 0; r < 8; ++r) {
        int oy = oy0 + wpx * 8 + r;
        ushort4 hv, lv;
#pragma unroll
        for (int j = 0; j < 4; ++j) {
          float v = acc[f][r][j] + bias4[j];
          if (MODE == M_BNRELU6) v = fminf(fmaxf(v, 0.f), 6.f);
          if (MODE == M_BIASRELU) v = fmaxf(v, 0.f);
          u16 h = f2bf(v);
          ((u16*)&hv)[j] = h;
          ((u16*)&lv)[j] = f2bf(v - bf2f(h));
        }
        size_t base = (((size_t)b * 128 + oy) * 128 + ox) * 64 + cb;
        *(ushort4*)(oxh + base) = hv;
        *(ushort4*)(oxl + base) = lv;
      }
    } else {
#pragma unroll
      for (int r = 0; r < 8; ++r) {
        int oy = oy0 + wpx * 8 + r;
        if (OUT_HW != 128 && (oy >= OUT_HW || ox >= OUT_HW)) continue;
#pragma unroll
        for (int j = 0; j < 4; ++j) {
          float v = acc[f][r][j] + bias4[j];
          if (MODE == M_BNRELU6) v = fminf(fmaxf(v, 0.f), 6.f);
          if (MODE == M_BIASRELU) v = fmaxf(v, 0.f);
          out[(((size_t)(b * 64) + cb + j) * OUT_HW + oy) * OUT_HW + ox] = v;
        }
      }
    }
  }
}

// ======= MFMA stride-2 conv3x3 via polyphase planes (split-bf16), + bias + relu =======
__global__ __launch_bounds__(256)
void convgc_mf(const u16* __restrict__ ph_h, const u16* __restrict__ ph_l,
               const u16* __restrict__ wh, const u16* __restrict__ wl,
               const float* __restrict__ bias, float* __restrict__ out)
{
  __shared__ char lds[81 * 144];             // 11664 B
  const int tid = threadIdx.x;
  const int lane = tid & 63;
  const int wv = __builtin_amdgcn_readfirstlane(tid >> 6);
  const int wco = wv & 1, wpx = wv >> 1;
  const int b = blockIdx.y;
  const int oy0 = (blockIdx.x >> 3) * 8, ox0 = (blockIdx.x & 7) * 8;
  const int l15 = lane & 15, l4 = lane >> 4;
  const int pr_ = l15 >> 3, pc_ = l15 & 7;
  const int aoff = l15 * 576 + l4 * 8;       // 9 taps * 64 cin
  const u16* wh0 = wh + wco * 32 * 576 + aoff;
  const u16* wl0 = wl + wco * 32 * 576 + aoff;

  f32x4 acc[2][2];
#pragma unroll
  for (int f = 0; f < 2; ++f)
#pragma unroll
    for (int g = 0; g < 2; ++g) { f32x4 z = {0.f, 0.f, 0.f, 0.f}; acc[f][g] = z; }

  const int PHA[9] = {0, 0, 0, 0, 1, 1, 2, 2, 3};
  const int OYO[9] = {0, 0, 1, 1, 0, 1, 0, 0, 0};
  const int OXO[9] = {0, 1, 0, 1, 0, 0, 0, 1, 0};

#pragma unroll 1
  for (int cc = 0; cc < 64; cc += 32) {
#pragma unroll
    for (int pos = 0; pos < 9; ++pos) {
      const int ph = PHA[pos];
      if (pos == 0 || pos == 4 || pos == 6 || pos == 8) {
        __syncthreads();
        for (int e = tid; e < 648; e += 256) {
          int pix = e >> 3, part = e & 7;
          int pu = pix / 9, pv = pix - pu * 9;
          int u = oy0 + pu, v = ox0 + pv;
          uint4 val = make_uint4(0u, 0u, 0u, 0u);
          if (u < 63 && v < 63) {
            const u16* s = ((part < 4) ? ph_h : ph_l)
                + (((size_t)(b * 4 + ph) * 63 + u) * 63 + v) * 64 + cc + (part & 3) * 8;
            val = *(const uint4*)s;
          }
          *(uint4*)(lds + pix * 144 + part * 16) = val;
        }
        __syncthreads();
      }
      bf16x8 ah0 = *(const bf16x8*)(wh0 + pos * 64 + cc);
      bf16x8 al0 = *(const bf16x8*)(wl0 + pos * 64 + cc);
      bf16x8 ah1 = *(const bf16x8*)(wh0 + 16 * 576 + pos * 64 + cc);
      bf16x8 al1 = *(const bf16x8*)(wl0 + 16 * 576 + pos * 64 + cc);
#pragma unroll
      for (int g = 0; g < 2; ++g) {
        const int lrow = wpx * 4 + g * 2 + pr_ + OYO[pos];
        const int lcol = pc_ + OXO[pos];
        const char* pb = lds + (lrow * 9 + lcol) * 144 + l4 * 16;
        bf16x8 bh = *(const bf16x8*)pb;
        bf16x8 bl = *(const bf16x8*)(pb + 64);
        acc[0][g] = __builtin_amdgcn_mfma_f32_16x16x32_bf16(ah0, bh, acc[0][g], 0, 0, 0);
        acc[1][g] = __builtin_amdgcn_mfma_f32_16x16x32_bf16(ah1, bh, acc[1][g], 0, 0, 0);
        acc[0][g] = __builtin_amdgcn_mfma_f32_16x16x32_bf16(ah0, bl, acc[0][g], 0, 0, 0);
        acc[0][g] = __builtin_amdgcn_mfma_f32_16x16x32_bf16(al0, bh, acc[0][g], 0, 0, 0);
        acc[1][g] = __builtin_amdgcn_mfma_f32_16x16x32_bf16(ah1, bl, acc[1][g], 0, 0, 0);
        acc[1][g] = __builtin_amdgcn_mfma_f32_16x16x32_bf16(al1, bh, acc[1][g], 0, 0, 0);
      }
    }
  }

  const int ox = ox0 + pc_;
#pragma unroll
  for (int f = 0; f < 2; ++f) {
    const int cb = wco * 32 + f * 16 + l4 * 4;
#pragma unroll
    for (int g = 0; g < 2; ++g) {
      int oy = oy0 + wpx * 4 + g * 2 + pr_;
      if (oy >= 62 || ox >= 62) continue;
#pragma unroll
      for (int j = 0; j < 4; ++j) {
        float v = acc[f][g][j] + bias[cb + j];
        out[(((size_t)(b * 64) + cb + j) * 62 + oy) * 62 + ox] = fmaxf(v, 0.f);
      }
    }
  }
}

// ================== MFMA DFT (split-bf16) ==================
// Round-13: blocks halved (32 rows / 16 cols per block) -> grid 1024, LDS 16.9 KB,
// 4+ blocks/CU for latency hiding. Single-stage/single-barrier kernels.

// rows forward: 32 rows/block; wave = (rowgroup wv&1) x (nf-half wv>>1).
__global__ __launch_bounds__(256)
void dft_rows_fwd_mf(const float* __restrict__ in, float* __restrict__ outC,
                     const u16* __restrict__ th, const u16* __restrict__ tl, int planeBase)
{
  __shared__ char lds[32 * 528];       // 16896
  const int tid = threadIdx.x;
  const int lane = tid & 63;
  const int wv = __builtin_amdgcn_readfirstlane(tid >> 6);
  const int l15 = lane & 15, l4 = lane >> 4;
  const int lp = blockIdx.x >> 2, rb = (blockIdx.x & 3) * 32;
  const float* src = in + (size_t)(planeBase + lp) * 15876;

  for (int e = tid; e < 4096; e += 256) {
    int row = e >> 7, k = e & 127;
    int gr = rb + row;
    float v = (gr < 126 && k < 126) ? src[(size_t)gr * 126 + k] : 0.f;
    u16 h = f2bf(v);
    char* p = lds + row * 528 + k * 2;
    *(u16*)p = h;
    *(u16*)(p + 256) = f2bf(v - bf2f(h));
  }
  __syncthreads();

  const int rg = wv & 1, nh = wv >> 1;
  f32x4 acc[4];
#pragma unroll
  for (int f = 0; f < 4; ++f) { f32x4 z = {0.f, 0.f, 0.f, 0.f}; acc[f] = z; }
#pragma unroll
  for (int cc = 0; cc < 128; cc += 32) {
    const char* pb = lds + (rg * 16 + l15) * 528 + cc * 2 + l4 * 16;
    bf16x8 bh = *(const bf16x8*)pb;
    bf16x8 bl = *(const bf16x8*)(pb + 256);
#pragma unroll
    for (int f = 0; f < 4; ++f) {
      const int ao = ((nh * 4 + f) * 16 + l15) * 128 + cc + l4 * 8;
      bf16x8 ah = *(const bf16x8*)(th + ao);
      bf16x8 al = *(const bf16x8*)(tl + ao);
      acc[f] = __builtin_amdgcn_mfma_f32_16x16x32_bf16(ah, bh, acc[f], 0, 0, 0);
      acc[f] = __builtin_amdgcn_mfma_f32_16x16x32_bf16(ah, bl, acc[f], 0, 0, 0);
      acc[f] = __builtin_amdgcn_mfma_f32_16x16x32_bf16(al, bh, acc[f], 0, 0, 0);
    }
  }
  const int row = rb + rg * 16 + l15;
  if (row < 126) {
    float* o = outC + (size_t)lp * 16128 + (size_t)row * 128;
#pragma unroll
    for (int f = 0; f < 4; ++f)
      *(f32x4*)(o + (nh * 4 + f) * 16 + l4 * 4) = acc[f];
  }
}

// cols transform: 16 k2-cols/block (fwd: conj W + |F| mask scale; inv: plain W).
template<bool FWD>
__global__ __launch_bounds__(256)
void dft_cols_mf(const float* __restrict__ inC, float* __restrict__ outC,
                 const u16* __restrict__ tch, const u16* __restrict__ tcl,
                 const u16* __restrict__ tsh, const u16* __restrict__ tsl)
{
  __shared__ char lds[16896];          // Sr [16col][528]; Si at +8448
  const int tid = threadIdx.x;
  const int lane = tid & 63;
  const int wv = __builtin_amdgcn_readfirstlane(tid >> 6);
  const int l15 = lane & 15, l4 = lane >> 4;
  const int lp = blockIdx.x >> 2, gbase = (blockIdx.x & 3) * 16;
  const float2* src = (const float2*)(inC + (size_t)lp * 16128);

  for (int e = tid; e < 2048; e += 256) {
    int col = e >> 7, k = e & 127;
    float2 v = make_float2(0.f, 0.f);
    if (k < 126) v = src[k * 64 + gbase + col];
    u16 hr = f2bf(v.x);
    u16 hi2 = f2bf(v.y);
    char* pr = lds + col * 528 + k * 2;
    char* pi = lds + 8448 + col * 528 + k * 2;
    *(u16*)pr = hr;        *(u16*)(pr + 256) = f2bf(v.x - bf2f(hr));
    *(u16*)pi = hi2;       *(u16*)(pi + 256) = f2bf(v.y - bf2f(hi2));
  }
  __syncthreads();

  f32x4 aRc[2], aRs[2], aIc[2], aIs[2];
#pragma unroll
  for (int a = 0; a < 2; ++a) {
    f32x4 z = {0.f, 0.f, 0.f, 0.f};
    aRc[a] = z; aRs[a] = z; aIc[a] = z; aIs[a] = z;
  }

#pragma unroll
  for (int cc = 0; cc < 128; cc += 32) {
    const char* pr = lds + l15 * 528 + cc * 2 + l4 * 16;
    bf16x8 brh = *(const bf16x8*)pr;
    bf16x8 brl = *(const bf16x8*)(pr + 256);
    const char* pi = lds + 8448 + l15 * 528 + cc * 2 + l4 * 16;
    bf16x8 bih = *(const bf16x8*)pi;
    bf16x8 bil = *(const bf16x8*)(pi + 256);
#pragma unroll
    for (int chf = 0; chf < 2; ++chf) {
      const int ao = (wv * 32 + chf * 16 + l15) * 128 + cc + l4 * 8;
      bf16x8 ach = *(const bf16x8*)(tch + ao);
      bf16x8 acl = *(const bf16x8*)(tcl + ao);
      bf16x8 ash = *(const bf16x8*)(tsh + ao);
      bf16x8 asl = *(const bf16x8*)(tsl + ao);
      aRc[chf] = __builtin_amdgcn_mfma_f32_16x16x32_bf16(ach, brh, aRc[chf], 0, 0, 0);
      aRc[chf] = __builtin_amdgcn_mfma_f32_16x16x32_bf16(ach, brl, aRc[chf], 0, 0, 0);
      aRc[chf] = __builtin_amdgcn_mfma_f32_16x16x32_bf16(acl, brh, aRc[chf], 0, 0, 0);
      aRs[chf] = __builtin_amdgcn_mfma_f32_16x16x32_bf16(ash, bih, aRs[chf], 0, 0, 0);
      aRs[chf] = __builtin_amdgcn_mfma_f32_16x16x32_bf16(ash, bil, aRs[chf], 0, 0, 0);
      aRs[chf] = __builtin_amdgcn_mfma_f32_16x16x32_bf16(asl, bih, aRs[chf], 0, 0, 0);
      aIc[chf] = __builtin_amdgcn_mfma_f32_16x16x32_bf16(ach, bih, aIc[chf], 0, 0, 0);
      aIc[chf] = __builtin_amdgcn_mfma_f32_16x16x32_bf16(ach, bil, aIc[chf], 0, 0, 0);
      aIc[chf] = __builtin_amdgcn_mfma_f32_16x16x32_bf16(acl, bih, aIc[chf], 0, 0, 0);
      aIs[chf] = __builtin_amdgcn_mfma_f32_16x16x32_bf16(ash, brh, aIs[chf], 0, 0, 0);
      aIs[chf] = __builtin_amdgcn_mfma_f32_16x16x32_bf16(ash, brl, aIs[chf], 0, 0, 0);
      aIs[chf] = __builtin_amdgcn_mfma_f32_16x16x32_bf16(asl, brh, aIs[chf], 0, 0, 0);
    }
  }

  float2* dst = (float2*)(outC + (size_t)lp * 16128);
  const int col = gbase + l15;
#pragma unroll
  for (int chf = 0; chf < 2; ++chf) {
    const int chb = wv * 32 + chf * 16 + l4 * 4;
#pragma unroll
    for (int j = 0; j < 4; ++j) {
      int ch = chb + j;
      if (ch >= 126) continue;
      float Cr, Ci;
      if (FWD) { Cr = aRc[chf][j] + aRs[chf][j]; Ci = aIc[chf][j] - aIs[chf][j]; }
      else     { Cr = aRc[chf][j] - aRs[chf][j]; Ci = aIc[chf][j] + aIs[chf][j]; }
      if (FWD) {
        int f1 = (ch <= 62) ? ch : ch - 126;
        int f2 = (col <= 62) ? col : col - 126;
        float sa = (f1 * f1 + f2 * f2 > 1600)
                     ? sqrtf(Cr * Cr + Ci * Ci) * (1.f / 15876.f) : 0.f;
        Cr *= sa; Ci *= sa;
      }
      dst[(size_t)ch * 64 + col] = make_float2(Cr, Ci);
    }
  }
}

// rows inverse + abs + fw-mix: 32 rows/block.
__global__ __launch_bounds__(256)
void dft_rows_inv_mix_mf(const float* __restrict__ inC, const float* __restrict__ xc0,
                         const float* __restrict__ gb_w,
                         const u16* __restrict__ th, const u16* __restrict__ tl,
                         float* __restrict__ out, int planeBase)
{
  __shared__ char lds[32 * 528];
  const int tid = threadIdx.x;
  const int lane = tid & 63;
  const int wv = __builtin_amdgcn_readfirstlane(tid >> 6);
  const int l15 = lane & 15, l4 = lane >> 4;
  const int lp = blockIdx.x >> 2, rb = (blockIdx.x & 3) * 32;
  const float* src = inC + (size_t)lp * 16128;

  for (int e = tid; e < 4096; e += 256) {
    int row = e >> 7, k = e & 127;
    int gr = rb + row;
    float v = (gr < 126) ? src[(size_t)gr * 128 + k] : 0.f;
    u16 h = f2bf(v);
    char* p = lds + row * 528 + k * 2;
    *(u16*)p = h;
    *(u16*)(p + 256) = f2bf(v - bf2f(h));
  }
  __syncthreads();

  const int rg = wv & 1, nh = wv >> 1;
  f32x4 acc[4];
#pragma unroll
  for (int f = 0; f < 4; ++f) { f32x4 z = {0.f, 0.f, 0.f, 0.f}; acc[f] = z; }
#pragma unroll
  for (int cc = 0; cc < 128; cc += 32) {
    const char* pb = lds + (rg * 16 + l15) * 528 + cc * 2 + l4 * 16;
    bf16x8 bh = *(const bf16x8*)pb;
    bf16x8 bl = *(const bf16x8*)(pb + 256);
#pragma unroll
    for (int f = 0; f < 4; ++f) {
      const int ao = ((nh * 4 + f) * 16 + l15) * 128 + cc + l4 * 8;
      bf16x8 ah = *(const bf16x8*)(th + ao);
      bf16x8 al = *(const bf16x8*)(tl + ao);
      acc[f] = __builtin_amdgcn_mfma_f32_16x16x32_bf16(ah, bh, acc[f], 0, 0, 0);
      acc[f] = __builtin_amdgcn_mfma_f32_16x16x32_bf16(ah, bl, acc[f], 0, 0, 0);
      acc[f] = __builtin_amdgcn_mfma_f32_16x16x32_bf16(al, bh, acc[f], 0, 0, 0);
    }
  }
  const int row = rb + rg * 16 + l15;
  if (row < 126) {
    float w0 = fmaxf(gb_w[0], 0.f), w1 = fmaxf(gb_w[1], 0.f);
    float iv = 1.f / (w0 + w1 + 1e-8f);
    const float w0i = w0 * iv, w1i = w1 * iv;
    size_t base = (size_t)(planeBase + lp) * 15876 + (size_t)row * 126;
#pragma unroll
    for (int f = 0; f < 4; ++f) {
      const int n20 = (nh * 4 + f) * 16 + l4 * 4;
#pragma unroll
      for (int j = 0; j < 4; ++j) {
        int n2 = n20 + j;
        if (n2 < 126)
          out[base + n2] = w0i * fabsf(acc[f][j]) + w1i * xc0[base + n2];
      }
    }
  }
}

// ---------------- maxpool 2x2 stride2: 62 -> 31 ----------------
__global__ __launch_bounds__(256) void mp2_k(const float* __restrict__ in, float* __restrict__ out)
{
  int idx = blockIdx.x * 256 + threadIdx.x;
  if (idx >= 512 * 31 * 31) return;
  int x = idx % 31, y = (idx / 31) % 31, p = idx / 961;
  const float* ip = in + (size_t)p * 3844 + (size_t)(2 * y) * 62 + 2 * x;
  out[idx] = fmaxf(fmaxf(ip[0], ip[1]), fmaxf(ip[62], ip[63]));
}

// -------- bilinear resize 31 -> 128, fused bf16 hi/lo NHWC split output --------
__global__ __launch_bounds__(256)
void resize_bf_k(const float* __restrict__ in, u16* __restrict__ xh, u16* __restrict__ xl)
{
  int idx = blockIdx.x * 256 + threadIdx.x;      // 8*128*128*16 = 2,097,152
  if (idx >= 2097152) return;
  int cg = idx & 15, x = (idx >> 4) & 127, y = (idx >> 11) & 127, b = idx >> 18;
  float sy = (y + 0.5f) * (31.f / 128.f) - 0.5f; sy = fminf(fmaxf(sy, 0.f), 30.f);
  float sx = (x + 0.5f) * (31.f / 128.f) - 0.5f; sx = fminf(fmaxf(sx, 0.f), 30.f);
  int y0 = (int)sy; float fy = sy - (float)y0; int y1 = min(y0 + 1, 30);
  int x0 = (int)sx; float fx = sx - (float)x0; int x1 = min(x0 + 1, 30);
  const float* base = in + (size_t)(b * 64 + cg * 4) * 961;
  ushort4 hv, lv;
#pragma unroll
  for (int k = 0; k < 4; ++k) {
    const float* ip = base + k * 961;
    float v = (1.f - fy) * ((1.f - fx) * ip[y0 * 31 + x0] + fx * ip[y0 * 31 + x1])
            + fy         * ((1.f - fx) * ip[y1 * 31 + x0] + fx * ip[y1 * 31 + x1]);
    u16 h = f2bf(v);
    ((u16*)&hv)[k] = h;
    ((u16*)&lv)[k] = f2bf(v - bf2f(h));
  }
  size_t o = (((size_t)b * 128 + y) * 128 + x) * 64 + cg * 4;
  *(ushort4*)(xh + o) = hv;
  *(ushort4*)(xl + o) = lv;
}

// ======= 1x1 conv (w_gc2) + log_softmax via MFMA (split-bf16), bf16 NHWC input =======
__global__ __launch_bounds__(256)
void pwlsm_mf(const u16* __restrict__ xh, const u16* __restrict__ xl,
              const u16* __restrict__ wh, const u16* __restrict__ wl,
              const float* __restrict__ bias, float* __restrict__ out)
{
  __shared__ char lds[17664];           // stage [64px][272B] (17408) / zs [64][69]f32 (17664)
  const int tid = threadIdx.x;
  const int lane = tid & 63;
  const int wv = __builtin_amdgcn_readfirstlane(tid >> 6);
  const int l15 = lane & 15, l4 = lane >> 4;
  const size_t px0 = (size_t)blockIdx.x * 64;

  for (int e = tid; e < 1024; e += 256) {
    int pix = e >> 4, part = e & 15;
    const u16* s = ((part < 8) ? xh : xl) + (px0 + pix) * 64 + (part & 7) * 8;
    char* d = lds + pix * 272 + ((part < 8) ? part * 16 : 128 + (part - 8) * 16);
    *(uint4*)d = *(const uint4*)s;
  }
  __syncthreads();

  f32x4 acc[4];
#pragma unroll
  for (int p = 0; p < 4; ++p) { f32x4 z = {0.f, 0.f, 0.f, 0.f}; acc[p] = z; }
  const int co16 = wv * 16;
  const u16* wa = wh + (size_t)(co16 + l15) * 64 + l4 * 8;
  const u16* wb = wl + (size_t)(co16 + l15) * 64 + l4 * 8;
#pragma unroll
  for (int cc = 0; cc < 64; cc += 32) {
    bf16x8 ah = *(const bf16x8*)(wa + cc);
    bf16x8 al = *(const bf16x8*)(wb + cc);
#pragma unroll
    for (int p = 0; p < 4; ++p) {
      const char* pb = lds + (16 * p + l15) * 272 + cc * 2 + l4 * 16;
      bf16x8 bh = *(const bf16x8*)pb;
      bf16x8 bl = *(const bf16x8*)(pb + 128);
      acc[p] = __builtin_amdgcn_mfma_f32_16x16x32_bf16(ah, bh, acc[p], 0, 0, 0);
      acc[p] = __builtin_amdgcn_mfma_f32_16x16x32_bf16(ah, bl, acc[p], 0, 0, 0);
      acc[p] = __builtin_amdgcn_mfma_f32_16x16x32_bf16(al, bh, acc[p], 0, 0, 0);
    }
  }
  float4 bv = *(const float4*)&bias[co16 + l4 * 4];
  __syncthreads();                      // all MFMA LDS reads done; reuse as zs
  float* zs = (float*)lds;
#pragma unroll
  for (int p = 0; p < 4; ++p) {
    int base = (16 * p + l15) * 69 + co16 + l4 * 4;
    zs[base + 0] = acc[p][0] + bv.x;
    zs[base + 1] = acc[p][1] + bv.y;
    zs[base + 2] = acc[p][2] + bv.z;
    zs[base + 3] = acc[p][3] + bv.w;
  }
  __syncthreads();
  if (tid < 64) {
    const float* z = zs + tid * 69;
    float m = -1e30f;
    for (int co = 0; co < 64; ++co) m = fmaxf(m, z[co]);
    float sum = 0.f;
    for (int co = 0; co < 64; ++co) sum += __expf(z[co] - m);
    float lse = m + __logf(sum);
    size_t g = px0 + tid;
    int b = (int)(g >> 14), px = (int)(g & 16383);
    float* op = out + ((size_t)b << 20) + px;
    for (int co = 0; co < 64; ++co) op[(size_t)co << 14] = z[co] - lse;
  }
}

// ======= final 1x1 conv (w_pw) via MFMA (split-bf16), fp32 NCHW input/output =======
__global__ __launch_bounds__(256)
void pw_mf(const float* __restrict__ in, const u16* __restrict__ wh,
           const u16* __restrict__ wl, float* __restrict__ out)
{
  __shared__ char lds[17408];           // stage [64px][272B] bf16 hi/lo
  const int tid = threadIdx.x;
  const int lane = tid & 63;
  const int wv = __builtin_amdgcn_readfirstlane(tid >> 6);
  const int l15 = lane & 15, l4 = lane >> 4;
  const size_t px0 = (size_t)blockIdx.x * 64;
  const int b = (int)(px0 >> 14), pxb = (int)(px0 & 16383);
  const float* ip = in + ((size_t)b << 20) + pxb;

  for (int e = tid; e < 4096; e += 256) {
    int cin = e >> 6, pix = e & 63;
    float v = ip[((size_t)cin << 14) + pix];
    u16 h = f2bf(v);
    *(u16*)(lds + pix * 272 + cin * 2)       = h;
    *(u16*)(lds + pix * 272 + 128 + cin * 2) = f2bf(v - bf2f(h));
  }
  __syncthreads();

  f32x4 acc[4];
#pragma unroll
  for (int p = 0; p < 4; ++p) { f32x4 z = {0.f, 0.f, 0.f, 0.f}; acc[p] = z; }
  const int co16 = wv * 16;
  const u16* wa = wh + (size_t)(co16 + l15) * 64 + l4 * 8;
  const u16* wb = wl + (size_t)(co16 + l15) * 64 + l4 * 8;
#pragma unroll
  for (int cc = 0; cc < 64; cc += 32) {
    bf16x8 ah = *(const bf16x8*)(wa + cc);
    bf16x8 al = *(const bf16x8*)(wb + cc);
#pragma unroll
    for (int p = 0; p < 4; ++p) {
      const char* pb = lds + (16 * p + l15) * 272 + cc * 2 + l4 * 16;
      bf16x8 bh = *(const bf16x8*)pb;
      bf16x8 bl = *(const bf16x8*)(pb + 128);
      acc[p] = __builtin_amdgcn_mfma_f32_16x16x32_bf16(ah, bh, acc[p], 0, 0, 0);
      acc[p] = __builtin_amdgcn_mfma_f32_16x16x32_bf16(ah, bl, acc[p], 0, 0, 0);
      acc[p] = __builtin_amdgcn_mfma_f32_16x16x32_bf16(al, bh, acc[p], 0, 0, 0);
    }
  }
  float* op = out + ((size_t)b << 20) + pxb;
#pragma unroll
  for (int p = 0; p < 4; ++p) {
    const int pix = 16 * p + l15;
    const int co = co16 + l4 * 4;
#pragma unroll
    for (int j = 0; j < 4; ++j)
      op[((size_t)(co + j) << 14) + pix] = acc[p][j];
  }
}

// ============ windowed attention: MFMA QKV (split-bf16) + register softmax ============
// Round-13: fmax / sum reduction chains split even/odd for ILP.
__global__ __launch_bounds__(256)
void attn_mf_k(const float* __restrict__ x, const u16* __restrict__ wqh,
               const u16* __restrict__ wql, const float* __restrict__ rpbt,
               float* __restrict__ o_out)
{
  __shared__ uint4 lds4[3200];          // 51200 B
  char* lds = (char*)lds4;
  const int tid = threadIdx.x;
  const int lane = tid & 63;
  const int wv = __builtin_amdgcn_readfirstlane(tid >> 6);
  const int b = blockIdx.x >> 8, gy = (blockIdx.x >> 4) & 15, gx = blockIdx.x & 15;
  const int y0 = gy * 8, x0 = gx * 8;
  const int l15 = lane & 15, l4 = lane >> 4;

  for (int e = tid; e < 4096; e += 256) {
    int cin = e >> 6, pix = e & 63;
    float v = x[((size_t)(b * 64 + cin) * 128 + (y0 + (pix >> 3))) * 128 + x0 + (pix & 7)];
    u16 h = f2bf(v);
    *(u16*)(lds + pix * 272 + cin * 2)       = h;
    *(u16*)(lds + pix * 272 + 128 + cin * 2) = f2bf(v - bf2f(h));
  }
  __syncthreads();

  f32x4 acc[3][4];
#pragma unroll
  for (int r = 0; r < 3; ++r)
#pragma unroll
    for (int p = 0; p < 4; ++p) { f32x4 z = {0.f, 0.f, 0.f, 0.f}; acc[r][p] = z; }
  const u16* wa = wqh + (size_t)(48 * wv + l15) * 64 + l4 * 8;
  const u16* wb = wql + (size_t)(48 * wv + l15) * 64 + l4 * 8;
#pragma unroll
  for (int cc = 0; cc < 64; cc += 32) {
    bf16x8 bh[4], bl[4];
#pragma unroll
    for (int p = 0; p < 4; ++p) {
      const char* pb = lds + (16 * p + l15) * 272 + cc * 2 + l4 * 16;
      bh[p] = *(const bf16x8*)pb;
      bl[p] = *(const bf16x8*)(pb + 128);
    }
#pragma unroll
    for (int r = 0; r < 3; ++r) {
      bf16x8 ah = *(const bf16x8*)(wa + r * 1024 + cc);
      bf16x8 al = *(const bf16x8*)(wb + r * 1024 + cc);
#pragma unroll
      for (int p = 0; p < 4; ++p) {
        acc[r][p] = __builtin_amdgcn_mfma_f32_16x16x32_bf16(ah, bh[p], acc[r][p], 0, 0, 0);
        acc[r][p] = __builtin_amdgcn_mfma_f32_16x16x32_bf16(ah, bl[p], acc[r][p], 0, 0, 0);
        acc[r][p] = __builtin_amdgcn_mfma_f32_16x16x32_bf16(al, bh[p], acc[r][p], 0, 0, 0);
      }
    }
  }
  __syncthreads();   // xt dead; safe to overwrite region A with Qs

#pragma unroll
  for (int r = 0; r < 3; ++r) {
    const int ch0 = 48 * wv + 16 * r + l4 * 4;
#pragma unroll
    for (int p = 0; p < 4; ++p) {
      const int pix = 16 * p + l15;
      if (ch0 < 64) {            // Q: Qs[ch][pix], pitch 65
#pragma unroll
        for (int j = 0; j < 4; ++j)
          *(float*)(lds + ((ch0 + j) * 65 + pix) * 4) = acc[r][p][j];
      } else {                   // K/V: KVT[pix][col], pitch 132
        const int col = (ch0 < 128) ? (ch0 - 64) : (64 + ch0 - 128);
        *(f32x4*)(lds + 17408 + pix * 528 + col * 4) = acc[r][p];
      }
    }
  }
  __syncthreads();

  const int row = y0 + (lane >> 3), col = x0 + (lane & 7);
  const int h0 = wv, h1 = wv + 4;
  float q0[8], q1[8];
#pragma unroll
  for (int d = 0; d < 8; ++d) {
    q0[d] = *(const float*)(lds + ((h0 * 8 + d) * 65 + lane) * 4);
    q1[d] = *(const float*)(lds + ((h1 * 8 + d) * 65 + lane) * 4);
  }
  const float* rb0 = rpbt + h0 * 4096;
  const float* rb1 = rpbt + h1 * 4096;
  float P0[64], P1[64];
#pragma unroll
  for (int j = 0; j < 64; ++j) { P0[j] = rb0[j * 64 + lane]; P1[j] = rb1[j * 64 + lane]; }
  float m0a = -1e30f, m0b = -1e30f, m1a = -1e30f, m1b = -1e30f;
#pragma unroll
  for (int j = 0; j < 64; ++j) {
    const char* kp = lds + 17408 + j * 528;
    float4 a0 = *(const float4*)(kp + (h0 * 8) * 4);
    float4 a1 = *(const float4*)(kp + (h0 * 8) * 4 + 16);
    float4 b0 = *(const float4*)(kp + (h1 * 8) * 4);
    float4 b1 = *(const float4*)(kp + (h1 * 8) * 4 + 16);
    float s0 = q0[0] * a0.x + q0[1] * a0.y + q0[2] * a0.z + q0[3] * a0.w
             + q0[4] * a1.x + q0[5] * a1.y + q0[6] * a1.z + q0[7] * a1.w;
    float s1 = q1[0] * b0.x + q1[1] * b0.y + q1[2] * b0.z + q1[3] * b0.w
             + q1[4] * b1.x + q1[5] * b1.y + q1[6] * b1.z + q1[7] * b1.w;
    s0 = s0 * ATT_SCALE + P0[j];
    s1 = s1 * ATT_SCALE + P1[j];
    P0[j] = s0; P1[j] = s1;
    if (j & 1) { m0b = fmaxf(m0b, s0); m1b = fmaxf(m1b, s1); }
    else       { m0a = fmaxf(m0a, s0); m1a = fmaxf(m1a, s1); }
  }
  float m0 = fmaxf(m0a, m0b), m1 = fmaxf(m1a, m1b);
  float s0a = 0.f, s0b = 0.f, s1a = 0.f, s1b = 0.f;
#pragma unroll
  for (int j = 0; j < 64; ++j) {
    float p0 = __expf(P0[j] - m0); P0[j] = p0;
    float p1 = __expf(P1[j] - m1); P1[j] = p1;
    if (j & 1) { s0b += p0; s1b += p1; }
    else       { s0a += p0; s1a += p1; }
  }
  float inv0 = 1.f / (s0a + s0b), inv1 = 1.f / (s1a + s1b);

  float acc0[8], acc1[8];
#pragma unroll
  for (int d = 0; d < 8; ++d) { acc0[d] = 0.f; acc1[d] = 0.f; }
#pragma unroll
  for (int j = 0; j < 64; ++j) {
    const char* vp = lds + 17408 + j * 528 + 256;   // V cols start at 64 floats
    float p0 = P0[j], p1 = P1[j];
    float4 v00 = *(const float4*)(vp + (h0 * 8) * 4);
    float4 v01 = *(const float4*)(vp + (h0 * 8) * 4 + 16);
    float4 v10 = *(const float4*)(vp + (h1 * 8) * 4);
    float4 v11 = *(const float4*)(vp + (h1 * 8) * 4 + 16);
    acc0[0] += p0 * v00.x; acc0[1] += p0 * v00.y; acc0[2] += p0 * v00.z; acc0[3] += p0 * v00.w;
    acc0[4] += p0 * v01.x; acc0[5] += p0 * v01.y; acc0[6] += p0 * v01.z; acc0[7] += p0 * v01.w;
    acc1[0] += p1 * v10.x; acc1[1] += p1 * v10.y; acc1[2] += p1 * v10.z; acc1[3] += p1 * v10.w;
    acc1[4] += p1 * v11.x; acc1[5] += p1 * v11.y; acc1[6] += p1 * v11.z; acc1[7] += p1 * v11.w;
  }
#pragma unroll
  for (int d = 0; d < 8; ++d) {
    o_out[((size_t)(b * 64 + h0 * 8 + d) * 128 + row) * 128 + col] = acc0[d] * inv0;
    o_out[((size_t)(b * 64 + h1 * 8 + d) * 128 + row) * 128 + col] = acc1[d] * inv1;
  }
}

// ------- directional avg pools + add local, LDS-tiled separable version -------
__global__ __launch_bounds__(256)
void avgadd_k(const float* __restrict__ o, const float* __restrict__ loc, float* __restrict__ out)
{
  __shared__ float t[24][128];
  const int tid = threadIdx.x;
  const int y0 = blockIdx.x * 16;
  const size_t p = blockIdx.y;
  const float* op = o + (p << 14);
  for (int e = tid; e < 24 * 128; e += 256) {
    int rr = e >> 7, x = e & 127;
    int r = y0 - 3 + rr;
    float v = 0.f;
    if (r >= 0 && r <= 128) { int r2 = (r == 128) ? 126 : r; v = op[r2 * 128 + x]; }
    t[rr][x] = v;
  }
  __syncthreads();
#pragma unroll
  for (int k = 0; k < 8; ++k) {
    int idx = k * 256 + tid;
    int ly = idx >> 7, x = idx & 127;
    float s1 = 0.f;
#pragma unroll
    for (int tt = 0; tt < 8; ++tt) s1 += t[ly + tt][x];
    float s2 = 0.f;
#pragma unroll
    for (int tt = 0; tt < 8; ++tt) {
      int cc = x - 3 + tt;
      if (cc >= 0 && cc <= 128) { int ss = (cc == 128) ? 126 : cc; s2 += t[ly + 3][ss]; }
    }
    size_t gi = (p << 14) + (size_t)(y0 + ly) * 128 + x;
    out[gi] = 0.125f * (s1 + s2) + loc[gi];
  }
}

// ---------------- depthwise 8x8 conv (pad_out + pad3, zero) + BN ----------------
__global__ __launch_bounds__(256)
void dw_k(const float* __restrict__ in, const float* __restrict__ w,
          const float* __restrict__ g, const float* __restrict__ bb, float* __restrict__ out)
{
  __shared__ float t[23 * 23];
  const int tid = threadIdx.x;
  const int tx = tid & 15, ty = tid >> 4;
  const int x0 = blockIdx.x * 16, y0 = blockIdx.y * 16;
  const int pc = blockIdx.z;
  const int c = pc & 63;
  const float* ip = in + (size_t)pc * 16384;
  for (int e = tid; e < 529; e += 256) {
    int yy = e / 23, xx = e % 23;
    int iy = y0 + yy - 3, ix = x0 + xx - 3;
    t[e] = (iy >= 0 && iy < 128 && ix >= 0 && ix < 128) ? ip[iy * 128 + ix] : 0.f;
  }
  __syncthreads();
  const float* wk = w + c * 64;
  float s = 0.f;
#pragma unroll
  for (int ky = 0; ky < 8; ++ky)
#pragma unroll
    for (int kx = 0; kx < 8; ++kx)
      s += t[(ty + ky) * 23 + tx + kx] * wk[ky * 8 + kx];
  out[(size_t)pc * 16384 + (y0 + ty) * 128 + x0 + tx] = s * (g[c] * BN_SC) + bb[c];
}

// =======================================================================
extern "C" void kernel_launch(void* const* d_in, const int* in_sizes, int n_in,
                              void* d_out, int out_size, void* d_ws, size_t ws_size,
                              hipStream_t stream)
{
  const float* x      = (const float*)d_in[0];
  const float* w_qkv  = (const float*)d_in[1];
  const float* w_l1   = (const float*)d_in[2];
  const float* g_l1   = (const float*)d_in[3];
  const float* b_l1   = (const float*)d_in[4];
  const float* w_l2   = (const float*)d_in[5];
  const float* g_l2   = (const float*)d_in[6];
  const float* b_l2   = (const float*)d_in[7];
  const float* f_cos  = (const float*)d_in[8];
  const float* f_sin  = (const float*)d_in[9];
  const float* gb_b1  = (const float*)d_in[10];
  const float* gb_b2  = (const float*)d_in[11];
  const float* gb_w   = (const float*)d_in[12];
  const float* w_post = (const float*)d_in[13];
  const float* g_post = (const float*)d_in[14];
  const float* b_post = (const float*)d_in[15];
  const float* w_gc   = (const float*)d_in[16];
  const float* b_gc   = (const float*)d_in[17];
  const float* w_gc1  = (const float*)d_in[18];
  const float* b_gc1  = (const float*)d_in[19];
  const float* w_gc2  = (const float*)d_in[20];
  const float* b_gc2  = (const float*)d_in[21];
  const float* rpb    = (const float*)d_in[22];
  const float* w_dw   = (const float*)d_in[23];
  const float* g_proj = (const float*)d_in[24];
  const float* b_proj = (const float*)d_in[25];
  const float* w_pw   = (const float*)d_in[26];
  const int*   relidx = (const int*)d_in[27];
  float* out = (float*)d_out;

  // Workspace map (within the proven 102,238,208-byte footprint):
  //  R1   [0,        33554432)   scratch A; PH planes (5-6); XC7 bf16 (9-10); attn o (11-12)
  //  R2   [33554432, 67108864)   scratch B; XH_A/XL_A; local (10-12); dw out (13-14)
  //  R3.. [67108864, 100663296)  FFT C1/C2; XH_B/XL_B; out0 (12-13)
  //  XC5  [100139008,102107136)  TB trig tables (DFT time, step 3) then mp2 out (7-8)
  //  W    [100663296,100827392)  per-conv split weights + BLS (re-gen per conv, after XC5 use)
  //  WQ   [100827392,100876544)  qkv split weights  — created AFTER resize (XC5 dead)
  //  WG   [100876544,100892928)  w_gc2 split weights — created AFTER resize
  //  WP   [100892928,100909312)  w_pw split weights  — created AFTER resize
  //  RPBT [102107136,102238208)
  char* ws = (char*)d_ws;
  float* R1   = (float*)(ws + 0);
  float* R2   = (float*)(ws + 33554432);
  float* R3   = (float*)(ws + 67108864);
  float* C1   = R3;
  float* C2   = (float*)(ws + 83623936);
  float* XC5  = (float*)(ws + 100139008);
  float* RPBT = (float*)(ws + 102107136);
  u16* XH_A = (u16*)(ws + 33554432);
  u16* XL_A = (u16*)(ws + 33554432 + 16777216);
  u16* XH_B = (u16*)(ws + 67108864);
  u16* XL_B = (u16*)(ws + 83886080);
  u16* PH_H = (u16*)(ws + 0);                 // 16,257,024 B
  u16* PH_L = (u16*)(ws + 16257024);          // ends 32,514,048
  u16* XC7H = (u16*)(ws + 0);                 // 16,777,216 B (steps 9-10)
  u16* XC7L = (u16*)(ws + 16777216);          // ends 33,554,432
  u16* TB   = (u16*)(ws + 100139008);         // 262,144 B DFT tables (XC5 region, DFT-time only)
  u16* WH   = (u16*)(ws + 100663296);
  u16* WL   = (u16*)(ws + 100745216);
  float* BLS = (float*)(ws + 100827136);
  u16* WQH  = (u16*)(ws + 100827392);         // 24576 B
  u16* WQL  = (u16*)(ws + 100851968);         // 24576 B, ends 100876544
  u16* WGH  = (u16*)(ws + 100876544);         // 8192 B
  u16* WGL  = (u16*)(ws + 100884736);         // 8192 B, ends 100892928
  u16* WPH  = (u16*)(ws + 100892928);         // 8192 B
  u16* WPL  = (u16*)(ws + 100901120);         // 8192 B, ends 100909312

  rpbprep_k<<<128, 256, 0, stream>>>(rpb, relidx, RPBT);

  // 1. LOCAL: bn(conv1x1) + bn(conv3x3) on x -> XH_B/XL_B  [MFMA, fused bf16-split out]
  wsplit_k<<<144, 256, 0, stream>>>(w_l1, g_l1, WH, WL, 64, 9, 0, 0, 10);
  wsplit_k<<<16, 256, 0, stream>>>(w_l2, g_l2, WH, WL, 64, 1, 0, 9, 10);
  bls_k<<<1, 64, 0, stream>>>(b_l1, b_l2, BLS);
  xsplit_k<128><<<1024, 256, 0, stream>>>(x, XH_A, XL_A);
  convmf_k<M_LOCAL, 10, 128, 128, 1, true><<<dim3(64, 8), 256, 0, stream>>>(
      XH_A, XL_A, WH, WL, BLS, nullptr, nullptr, XH_B, XL_B);

  // 2. GABOR: valid conv, cos||sin + biases -> R2 (xc0, 126x126)
  wsplit_k<<<72, 256, 0, stream>>>(f_cos, nullptr, WH, WL, 32, 9, 0, 0, 9);
  wsplit_k<<<72, 256, 0, stream>>>(f_sin, nullptr, WH, WL, 32, 9, 32, 0, 9);
  convmf_k<M_GABOR, 9, 128, 126, 0, false><<<dim3(64, 8), 256, 0, stream>>>(
      XH_B, XL_B, WH, WL, gb_b1, gb_b2, R2, nullptr, nullptr);

  // 3. fft_h + fw-mix via MFMA DFT, 2 chunks of 256 planes -> R1 (xc1)
  tprep_k<<<256, 256, 0, stream>>>(TB);
  for (int chunk = 0; chunk < 2; ++chunk) {
    int pb = chunk * 256;
    dft_rows_fwd_mf<<<1024, 256, 0, stream>>>(R2, C1, TB, TB + 16384, pb);
    dft_cols_mf<true><<<1024, 256, 0, stream>>>(C1, C2, TB + 32768, TB + 49152,
                                                TB + 65536, TB + 81920);
    dft_cols_mf<false><<<1024, 256, 0, stream>>>(C2, C1, TB + 32768, TB + 49152,
                                                 TB + 65536, TB + 81920);
    dft_rows_inv_mix_mf<<<1024, 256, 0, stream>>>(C1, R2, gb_w, TB + 98304, TB + 114688,
                                                  R1, pb);
  }

  // 4. relu6(bn(conv3x3 w_post)) -> R2 (xc2)
  wsplit_k<<<144, 256, 0, stream>>>(w_post, g_post, WH, WL, 64, 9, 0, 0, 9);
  xsplit_k<126><<<1008, 256, 0, stream>>>(R1, XH_B, XL_B);
  convmf_k<M_BNRELU6, 9, 126, 126, 1, false><<<dim3(64, 8), 256, 0, stream>>>(
      XH_B, XL_B, WH, WL, b_post, nullptr, R2, nullptr, nullptr);

  // 5. fused maxpool(2x2 s1) + stride-2 polyphase split -> PH planes (R1 region)
  mpsplit_k<<<1008, 256, 0, stream>>>(R2, PH_H, PH_L);

  // 6. MFMA stride-2 conv w_gc + bias + relu -> R3 (62^2)
  wsplit_gc_k<<<144, 256, 0, stream>>>(w_gc, WH, WL);
  convgc_mf<<<dim3(64, 8), 256, 0, stream>>>(PH_H, PH_L, WH, WL, b_gc, R3);

  // 7. maxpool 2x2 s2 -> XC5 (31^2)   [clobbers TB/W/WQ/WG/WP regions]
  mp2_k<<<1922, 256, 0, stream>>>(R3, XC5);
  // 8. bilinear resize 31 -> 128 + fused bf16 split -> XH_B/XL_B   [last XC5 reader]
  resize_bf_k<<<8192, 256, 0, stream>>>(XC5, XH_B, XL_B);

  // qkv + w_gc2 + w_pw weight splits — AFTER resize so XC5 can no longer clobber them
  wsplit_k<<<48, 256, 0, stream>>>(w_qkv, nullptr, WQH, WQL, 192, 1, 0, 0, 1);
  wsplit_k<<<16, 256, 0, stream>>>(w_gc2, nullptr, WGH, WGL, 64, 1, 0, 0, 1);
  wsplit_k<<<16, 256, 0, stream>>>(w_pw, nullptr, WPH, WPL, 64, 1, 0, 0, 1);

  // 9. relu(conv3x3 w_gc1 + b) -> XC7 bf16 NHWC (R1 region)  [fused split + relu out]
  wsplit_k<<<144, 256, 0, stream>>>(w_gc1, nullptr, WH, WL, 64, 9, 0, 0, 9);
  convmf_k<M_BIASRELU, 9, 128, 128, 1, true><<<dim3(64, 8), 256, 0, stream>>>(
      XH_B, XL_B, WH, WL, b_gc1, nullptr, nullptr, XC7H, XC7L);

  // 10. 1x1 conv w_gc2 + log_softmax -> R2 (local)   [MFMA]
  pwlsm_mf<<<2048, 256, 0, stream>>>(XC7H, XC7L, WGH, WGL, b_gc2, R2);
  // 11. window attention -> R1 (o)   [XC7 dead]
  attn_mf_k<<<2048, 256, 0, stream>>>(x, WQH, WQL, RPBT, R1);
  // 12. ox + oy + local -> R3 (out0)   [LDS-tiled separable]
  avgadd_k<<<dim3(8, 512), 256, 0, stream>>>(R1, R2, R3);
  // 13. depthwise 8x8 + bn -> R2
  dw_k<<<dim3(8, 8, 512), 256, 0, stream>>>(R3, w_dw, g_proj, b_proj, R2);
  // 14. 1x1 conv w_pw -> d_out   [MFMA]
  pw_mf<<<2048, 256, 0, stream>>>(R2, WPH, WPL, out);
  (void)in_sizes; (void)n_in; (void)out_size; (void)ws_size;
}

// Round 15
// 826.588 us; speedup vs baseline: 1.0511x; 1.0511x over previous
//
#include <hip/hip_runtime.h>
#include <math.h>

#define BN_SC 0.9999950000375f
#define P2N   (6.283185307179586f / 126.f)
#define ATT_SCALE 0.35355339059327373f

typedef float v4f __attribute__((ext_vector_type(4)));
typedef short bf16x8 __attribute__((ext_vector_type(8)));
typedef float f32x4 __attribute__((ext_vector_type(4)));
typedef unsigned short u16;

enum { M_LOCAL = 0, M_GABOR = 1, M_BNRELU6 = 2, M_BIASRELU = 3 };

__device__ __forceinline__ u16 f2bf(float f) {
  unsigned u = __float_as_uint(f);
  return (u16)((u + 0x7FFFu + ((u >> 16) & 1u)) >> 16);
}
__device__ __forceinline__ float bf2f(u16 h) {
  return __uint_as_float(((unsigned)h) << 16);
}

// ------------- rpb bias pre-gather: rpbt[h][j*64+i] = rpb[relidx[i*64+j]*8+h] -------------
__global__ __launch_bounds__(256) void rpbprep_k(
    const float* __restrict__ rpb, const int* __restrict__ relidx, float* __restrict__ rpbt)
{
  int idx = blockIdx.x * 256 + threadIdx.x; // 32768
  int h = idx >> 12, r = idx & 4095, j = r >> 6, i = r & 63;
  rpbt[idx] = rpb[relidx[i * 64 + j] * 8 + h];
}

// ---------------- bias add (local branch: b_l1 + b_l2) ----------------
__global__ void bls_k(const float* __restrict__ a, const float* __restrict__ b,
                      float* __restrict__ o)
{ int i = threadIdx.x; o[i] = a[i] + b[i]; }

// -------- weight split: fp32 [nco][64][ntap] -> bf16 hi/lo [co_off+co][NT][64] --------
__global__ __launch_bounds__(256)
void wsplit_k(const float* __restrict__ w, const float* __restrict__ gsc,
              u16* __restrict__ wh, u16* __restrict__ wl,
              int nco, int ntap, int co_off, int tap_off, int NT)
{
  int i = blockIdx.x * 256 + threadIdx.x;
  if (i >= nco * 64 * ntap) return;
  int t = i % ntap, q = i / ntap;
  int cin = q & 63, co = q >> 6;
  float v = w[i];
  if (gsc) v *= gsc[co_off + co] * BN_SC;
  u16 h = f2bf(v);
  u16 l = f2bf(v - bf2f(h));
  int dst = ((co_off + co) * NT + tap_off + t) * 64 + cin;
  wh[dst] = h; wl[dst] = l;
}

// -------- weight split for stride-2 conv, phase-grouped tap order --------
__global__ __launch_bounds__(256)
void wsplit_gc_k(const float* __restrict__ w, u16* __restrict__ wh, u16* __restrict__ wl)
{
  int i = blockIdx.x * 256 + threadIdx.x;   // 64*64*9 = 36864
  if (i >= 36864) return;
  int t = i % 9, q = i / 9;
  int cin = q & 63, co = q >> 6;
  const int POS[9] = {0, 4, 1, 6, 8, 7, 2, 5, 3};  // pos_of_tap
  float v = w[i];
  u16 h = f2bf(v);
  u16 l = f2bf(v - bf2f(h));
  int dst = (co * 9 + POS[t]) * 64 + cin;
  wh[dst] = h; wl[dst] = l;
}

// -------- DFT trig tables, bf16 hi/lo, 4 tables of [128 ch][128 k] --------
__global__ __launch_bounds__(256)
void tprep_k(u16* __restrict__ tb)
{
  int idx = blockIdx.x * 256 + threadIdx.x;   // 65536
  int tab = idx >> 14, r = idx & 16383;
  int ch = r >> 7, k = r & 127;
  float v = 0.f;
  if (tab == 0) {
    int k2 = ch >> 1;
    if (k < 126) {
      int m = (k * k2) % 126;
      float s, c; sincosf(P2N * (float)m, &s, &c);
      v = (ch & 1) ? -s : c;
    }
  } else if (tab == 1) {
    if (ch < 126 && k < 126) { int m = (ch * k) % 126; v = cosf(P2N * (float)m); }
  } else if (tab == 2) {
    if (ch < 126 && k < 126) { int m = (ch * k) % 126; v = sinf(P2N * (float)m); }
  } else {
    int k2 = k >> 1;
    if (ch < 126) {
      float w = (k2 == 0 || k2 == 63) ? 1.f : 2.f;
      int m = (ch * k2) % 126;
      float s, c; sincosf(P2N * (float)m, &s, &c);
      v = (k & 1) ? -w * s : w * c;
    }
  }
  u16 h = f2bf(v), l = f2bf(v - bf2f(h));
  tb[tab * 32768 + r] = h;
  tb[tab * 32768 + 16384 + r] = l;
}

// -------- input split+transpose: fp32 NCHW [8][64][HW][HW] -> bf16 hi/lo NHWC --------
template<int HW>
__global__ __launch_bounds__(256)
void xsplit_k(const float* __restrict__ in, u16* __restrict__ xh, u16* __restrict__ xl)
{
  __shared__ float t[64 * (HW + 1)];
  const int by = blockIdx.x;          // b*HW + y
  const int tid = threadIdx.x;
  const int b = by / HW, y = by - b * HW;
  const float* ip = in + (size_t)b * 64 * HW * HW + (size_t)y * HW;
  for (int e = tid; e < 64 * HW; e += 256) {
    int cin = e / HW, x = e - cin * HW;
    t[cin * (HW + 1) + x] = ip[(size_t)cin * HW * HW + x];
  }
  __syncthreads();
  u16* oh = xh + (size_t)by * HW * 64;
  u16* ol = xl + (size_t)by * HW * 64;
  for (int e = tid; e < 64 * HW; e += 256) {
    int x = e >> 6, cin = e & 63;
    float v = t[cin * (HW + 1) + x];
    u16 h = f2bf(v);
    oh[e] = h;
    ol[e] = f2bf(v - bf2f(h));
  }
}

// -------- fused maxpool(2x2,s1) + stride-2 phase split: 126^2 fp32 -> 4x 63^2 bf16 NHWC --------
__global__ __launch_bounds__(256)
void mpsplit_k(const float* __restrict__ in, u16* __restrict__ ph_h, u16* __restrict__ ph_l)
{
  __shared__ float rm[126 * 65];      // [col][cin], pitch 65: rowmax of 2 input rows
  const int tid = threadIdx.x;
  const int bx = blockIdx.x;          // b*126 + py*63 + u
  const int b = bx / 126, r = bx % 126;
  const int py = r / 63, u = r % 63;
  const bool valid_u = !(py == 1 && u == 62);
  if (valid_u) {
    const int r0 = 2 * u + py;
    const float* ip = in + (size_t)b * 64 * 15876;
    for (int e = tid; e < 64 * 126; e += 256) {
      int cin = e / 126, col = e - cin * 126;
      const float* p = ip + (size_t)cin * 15876 + (size_t)r0 * 126 + col;
      rm[col * 65 + cin] = fmaxf(p[0], p[126]);
    }
  }
  __syncthreads();
  for (int e = tid; e < 8064; e += 256) {   // 2 px * 63 v * 64 cin
    int px = e / 4032;
    int rr = e - px * 4032;
    int v = rr >> 6, cin = rr & 63;
    float val = 0.f;
    if (valid_u && !(px == 1 && v == 62)) {
      int c0 = 2 * v + px;
      val = fmaxf(rm[c0 * 65 + cin], rm[(c0 + 1) * 65 + cin]);
    }
    u16 h = f2bf(val);
    size_t dst = (((size_t)(b * 4 + py * 2 + px) * 63 + u) * 63 + v) * 64 + cin;
    ph_h[dst] = h;
    ph_l[dst] = f2bf(val - bf2f(h));
  }
}

// ================= MFMA conv3x3 (split-bf16, 3-MFMA fp32-accurate) =================
template<int MODE, int NT, int IN_HW, int OUT_HW, int PAD, bool OUTBF>
__global__ __launch_bounds__(256, 3)
void convmf_k(const u16* __restrict__ xh, const u16* __restrict__ xl,
              const u16* __restrict__ wh, const u16* __restrict__ wl,
              const float* __restrict__ ba, const float* __restrict__ bb,
              float* __restrict__ out, u16* __restrict__ oxh, u16* __restrict__ oxl)
{
  __shared__ uint4 lds4[2916];               // 324 * 144 B = 46656
  char* lds = (char*)lds4;
  const int tid = threadIdx.x;
  const int lane = tid & 63;
  const int wv = __builtin_amdgcn_readfirstlane(tid >> 6);
  const int wco = wv & 1, wpx = wv >> 1;
  const int b = blockIdx.y;
  const int oy0 = (blockIdx.x >> 3) * 16, ox0 = (blockIdx.x & 7) * 16;
  const int iy0 = oy0 - PAD, ix0 = ox0 - PAD;
  const int l15 = lane & 15, l4 = lane >> 4;
  const int bboff = l15 * 144 + l4 * 16;
  const int aoff  = l15 * (NT * 64) + l4 * 8;
  const u16* wh0 = wh + wco * 32 * NT * 64 + aoff;
  const u16* wl0 = wl + wco * 32 * NT * 64 + aoff;

  f32x4 acc[2][8];
#pragma unroll
  for (int f = 0; f < 2; ++f)
#pragma unroll
    for (int r = 0; r < 8; ++r) { f32x4 z = {0.f, 0.f, 0.f, 0.f}; acc[f][r] = z; }

#pragma unroll 1
  for (int cc = 0; cc < 64; cc += 32) {
    __syncthreads();
    for (int e = tid; e < 2592; e += 256) {
      int pix = e >> 3, part = e & 7;
      int lr = pix / 18, lc = pix - lr * 18;
      int iy = iy0 + lr, ix = ix0 + lc;
      uint4 v = make_uint4(0u, 0u, 0u, 0u);
      if ((unsigned)iy < (unsigned)IN_HW && (unsigned)ix < (unsigned)IN_HW) {
        const u16* s = ((part < 4) ? xh : xl)
            + ((size_t)(b * IN_HW + iy) * IN_HW + ix) * 64 + cc + (part & 3) * 8;
        v = *(const uint4*)s;
      }
      *(uint4*)(lds + pix * 144 + part * 16) = v;
    }
    __syncthreads();

    bf16x8 ah0 = *(const bf16x8*)(wh0 + cc);
    bf16x8 al0 = *(const bf16x8*)(wl0 + cc);
    bf16x8 ah1 = *(const bf16x8*)(wh0 + 16 * NT * 64 + cc);
    bf16x8 al1 = *(const bf16x8*)(wl0 + 16 * NT * 64 + cc);

#pragma unroll 1
    for (int t = 0; t < NT; ++t) {
      int tn = (t + 1 < NT) ? t + 1 : t;
      bf16x8 nh0 = *(const bf16x8*)(wh0 + tn * 64 + cc);
      bf16x8 nl0 = *(const bf16x8*)(wl0 + tn * 64 + cc);
      bf16x8 nh1 = *(const bf16x8*)(wh0 + 16 * NT * 64 + tn * 64 + cc);
      bf16x8 nl1 = *(const bf16x8*)(wl0 + 16 * NT * 64 + tn * 64 + cc);
      int te = (t >= 9) ? 4 : t;            // tap 9 (1x1) = center (1,1)
      int dy = te / 3;
      int dx = te - dy * 3;
      const char* pb = lds + ((wpx * 8 + dy) * 18 + dx) * 144 + bboff;
#pragma unroll
      for (int r = 0; r < 8; ++r) {
        bf16x8 bh = *(const bf16x8*)(pb + r * 2592);
        bf16x8 bl = *(const bf16x8*)(pb + r * 2592 + 64);
        acc[0][r] = __builtin_amdgcn_mfma_f32_16x16x32_bf16(ah0, bh, acc[0][r], 0, 0, 0);
        acc[1][r] = __builtin_amdgcn_mfma_f32_16x16x32_bf16(ah1, bh, acc[1][r], 0, 0, 0);
        acc[0][r] = __builtin_amdgcn_mfma_f32_16x16x32_bf16(ah0, bl, acc[0][r], 0, 0, 0);
        acc[0][r] = __builtin_amdgcn_mfma_f32_16x16x32_bf16(al0, bh, acc[0][r], 0, 0, 0);
        acc[1][r] = __builtin_amdgcn_mfma_f32_16x16x32_bf16(ah1, bl, acc[1][r], 0, 0, 0);
        acc[1][r] = __builtin_amdgcn_mfma_f32_16x16x32_bf16(al1, bh, acc[1][r], 0, 0, 0);
      }
      ah0 = nh0; al0 = nl0; ah1 = nh1; al1 = nl1;
    }
  }

  const int ox = ox0 + l15;
#pragma unroll
  for (int f = 0; f < 2; ++f) {
    const int cb = wco * 32 + f * 16 + l4 * 4;
    float bias4[4];
#pragma unroll
    for (int j = 0; j < 4; ++j) {
      int c = cb + j;
      bias4[j] = (MODE == M_GABOR && c >= 32) ? bb[c - 32] : ba[c];
    }
    if (OUTBF) {
#pragma unroll
      for (int r = 0; r < 8; ++r) {
        int oy = oy0 + wpx * 8 + r;
        ushort4 hv, lv;
#pragma unroll
        for (int j = 0; j < 4; ++j) {
          float v = acc[f][r][j] + bias4[j];
          if (MODE == M_BNRELU6) v = fminf(fmaxf(v, 0.f), 6.f);
          if (MODE == M_BIASRELU) v = fmaxf(v, 0.f);
          u16 h = f2bf(v);
          ((u16*)&hv)[j] = h;
          ((u16*)&lv)[j] = f2bf(v - bf2f(h));
        }
        size_t base = (((size_t)b * 128 + oy) * 128 + ox) * 64 + cb;
        *(ushort4*)(oxh + base) = hv;
        *(ushort4*)(oxl + base) = lv;
      }
    } else {
#pragma unroll
      for (int r = 0; r < 8; ++r) {
        int oy = oy0 + wpx * 8 + r;
        if (OUT_HW != 128 && (oy >= OUT_HW || ox >= OUT_HW)) continue;
#pragma unroll
        for (int j = 0; j < 4; ++j) {
          float v = acc[f][r][j] + bias4[j];
          if (MODE == M_BNRELU6) v = fminf(fmaxf(v, 0.f), 6.f);
          if (MODE == M_BIASRELU) v = fmaxf(v, 0.f);
          out[(((size_t)(b * 64) + cb + j) * OUT_HW + oy) * OUT_HW + ox] = v;
        }
      }
    }
  }
}

// ======= MFMA stride-2 conv3x3 via polyphase planes (split-bf16) + relu =======
// Fused 2x2 s2 maxpool epilogue -> writes 31x31 pooled output only.
__global__ __launch_bounds__(256)
void convgc_mf(const u16* __restrict__ ph_h, const u16* __restrict__ ph_l,
               const u16* __restrict__ wh, const u16* __restrict__ wl,
               const float* __restrict__ bias, float* __restrict__ pooled)
{
  __shared__ char lds[16896];                // staging 11664 B; pool reuse 64*66*4 = 16896 B
  const int tid = threadIdx.x;
  const int lane = tid & 63;
  const int wv = __builtin_amdgcn_readfirstlane(tid >> 6);
  const int wco = wv & 1, wpx = wv >> 1;
  const int b = blockIdx.y;
  const int oy0 = (blockIdx.x >> 3) * 8, ox0 = (blockIdx.x & 7) * 8;
  const int l15 = lane & 15, l4 = lane >> 4;
  const int pr_ = l15 >> 3, pc_ = l15 & 7;
  const int aoff = l15 * 576 + l4 * 8;       // 9 taps * 64 cin
  const u16* wh0 = wh + wco * 32 * 576 + aoff;
  const u16* wl0 = wl + wco * 32 * 576 + aoff;

  f32x4 acc[2][2];
#pragma unroll
  for (int f = 0; f < 2; ++f)
#pragma unroll
    for (int g = 0; g < 2; ++g) { f32x4 z = {0.f, 0.f, 0.f, 0.f}; acc[f][g] = z; }

  const int PHA[9] = {0, 0, 0, 0, 1, 1, 2, 2, 3};
  const int OYO[9] = {0, 0, 1, 1, 0, 1, 0, 0, 0};
  const int OXO[9] = {0, 1, 0, 1, 0, 0, 0, 1, 0};

#pragma unroll 1
  for (int cc = 0; cc < 64; cc += 32) {
#pragma unroll
    for (int pos = 0; pos < 9; ++pos) {
      const int ph = PHA[pos];
      if (pos == 0 || pos == 4 || pos == 6 || pos == 8) {
        __syncthreads();
        for (int e = tid; e < 648; e += 256) {
          int pix = e >> 3, part = e & 7;
          int pu = pix / 9, pv = pix - pu * 9;
          int u = oy0 + pu, v = ox0 + pv;
          uint4 val = make_uint4(0u, 0u, 0u, 0u);
          if (u < 63 && v < 63) {
            const u16* s = ((part < 4) ? ph_h : ph_l)
                + (((size_t)(b * 4 + ph) * 63 + u) * 63 + v) * 64 + cc + (part & 3) * 8;
            val = *(const uint4*)s;
          }
          *(uint4*)(lds + pix * 144 + part * 16) = val;
        }
        __syncthreads();
      }
      bf16x8 ah0 = *(const bf16x8*)(wh0 + pos * 64 + cc);
      bf16x8 al0 = *(const bf16x8*)(wl0 + pos * 64 + cc);
      bf16x8 ah1 = *(const bf16x8*)(wh0 + 16 * 576 + pos * 64 + cc);
      bf16x8 al1 = *(const bf16x8*)(wl0 + 16 * 576 + pos * 64 + cc);
#pragma unroll
      for (int g = 0; g < 2; ++g) {
        const int lrow = wpx * 4 + g * 2 + pr_ + OYO[pos];
        const int lcol = pc_ + OXO[pos];
        const char* pb = lds + (lrow * 9 + lcol) * 144 + l4 * 16;
        bf16x8 bh = *(const bf16x8*)pb;
        bf16x8 bl = *(const bf16x8*)(pb + 64);
        acc[0][g] = __builtin_amdgcn_mfma_f32_16x16x32_bf16(ah0, bh, acc[0][g], 0, 0, 0);
        acc[1][g] = __builtin_amdgcn_mfma_f32_16x16x32_bf16(ah1, bh, acc[1][g], 0, 0, 0);
        acc[0][g] = __builtin_amdgcn_mfma_f32_16x16x32_bf16(ah0, bl, acc[0][g], 0, 0, 0);
        acc[0][g] = __builtin_amdgcn_mfma_f32_16x16x32_bf16(al0, bh, acc[0][g], 0, 0, 0);
        acc[1][g] = __builtin_amdgcn_mfma_f32_16x16x32_bf16(ah1, bl, acc[1][g], 0, 0, 0);
        acc[1][g] = __builtin_amdgcn_mfma_f32_16x16x32_bf16(al1, bh, acc[1][g], 0, 0, 0);
      }
    }
  }

  // ---- epilogue: relu+bias into LDS pool tile [ch][66] (pitch 66 floats), then 2x2 s2 max ----
  __syncthreads();                           // all MFMA LDS reads done; reuse as pool
  float* pool = (float*)lds;
#pragma unroll
  for (int f = 0; f < 2; ++f) {
    const int cb = wco * 32 + f * 16 + l4 * 4;
#pragma unroll
    for (int g = 0; g < 2; ++g) {
      const int ly = wpx * 4 + g * 2 + pr_;
#pragma unroll
      for (int j = 0; j < 4; ++j) {
        float v = fmaxf(acc[f][g][j] + bias[cb + j], 0.f);
        pool[(cb + j) * 66 + ly * 8 + pc_] = v;
      }
    }
  }
  __syncthreads();
  const int py0 = oy0 >> 1, px0 = ox0 >> 1;
  for (int e = tid; e < 1024; e += 256) {
    int ch = e >> 4, py = (e >> 2) & 3, px = e & 3;
    int gy = py0 + py, gx = px0 + px;
    if (gy < 31 && gx < 31) {
      const float* pc = pool + ch * 66 + (2 * py) * 8 + 2 * px;
      float m = fmaxf(fmaxf(pc[0], pc[1]), fmaxf(pc[8], pc[9]));
      pooled[(size_t)(b * 64 + ch) * 961 + gy * 31 + gx] = m;
    }
  }
}

// ================== MFMA DFT (split-bf16), round-12 proven geometry ==================

__global__ __launch_bounds__(256)
void dft_rows_fwd_mf(const float* __restrict__ in, float* __restrict__ outC,
                     const u16* __restrict__ th, const u16* __restrict__ tl, int planeBase)
{
  __shared__ char lds[64 * 528];
  const int tid = threadIdx.x;
  const int lane = tid & 63;
  const int wv = __builtin_amdgcn_readfirstlane(tid >> 6);
  const int l15 = lane & 15, l4 = lane >> 4;
  const int lp = blockIdx.x >> 1, rb = (blockIdx.x & 1) * 64;
  const float* src = in + (size_t)(planeBase + lp) * 15876;

  for (int e = tid; e < 8192; e += 256) {
    int row = e >> 7, k = e & 127;
    int gr = rb + row;
    float v = (gr < 126 && k < 126) ? src[(size_t)gr * 126 + k] : 0.f;
    u16 h = f2bf(v);
    char* p = lds + row * 528 + k * 2;
    *(u16*)p = h;
    *(u16*)(p + 256) = f2bf(v - bf2f(h));
  }
  __syncthreads();

  f32x4 acc[8];
#pragma unroll
  for (int nf = 0; nf < 8; ++nf) { f32x4 z = {0.f, 0.f, 0.f, 0.f}; acc[nf] = z; }
#pragma unroll
  for (int cc = 0; cc < 128; cc += 32) {
    const char* pb = lds + (wv * 16 + l15) * 528 + cc * 2 + l4 * 16;
    bf16x8 bh = *(const bf16x8*)pb;
    bf16x8 bl = *(const bf16x8*)(pb + 256);
#pragma unroll
    for (int nf = 0; nf < 8; ++nf) {
      const int ao = (nf * 16 + l15) * 128 + cc + l4 * 8;
      bf16x8 ah = *(const bf16x8*)(th + ao);
      bf16x8 al = *(const bf16x8*)(tl + ao);
      acc[nf] = __builtin_amdgcn_mfma_f32_16x16x32_bf16(ah, bh, acc[nf], 0, 0, 0);
      acc[nf] = __builtin_amdgcn_mfma_f32_16x16x32_bf16(ah, bl, acc[nf], 0, 0, 0);
      acc[nf] = __builtin_amdgcn_mfma_f32_16x16x32_bf16(al, bh, acc[nf], 0, 0, 0);
    }
  }
  const int row = rb + wv * 16 + l15;
  if (row < 126) {
    float* o = outC + (size_t)lp * 16128 + (size_t)row * 128;
#pragma unroll
    for (int nf = 0; nf < 8; ++nf)
      *(f32x4*)(o + nf * 16 + l4 * 4) = acc[nf];
  }
}

template<bool FWD>
__global__ __launch_bounds__(256)
void dft_cols_mf(const float* __restrict__ inC, float* __restrict__ outC,
                 const u16* __restrict__ tch, const u16* __restrict__ tcl,
                 const u16* __restrict__ tsh, const u16* __restrict__ tsl)
{
  __shared__ char lds[33792];          // Sr [32col][528]; Si at +16896
  const int tid = threadIdx.x;
  const int lane = tid & 63;
  const int wv = __builtin_amdgcn_readfirstlane(tid >> 6);
  const int l15 = lane & 15, l4 = lane >> 4;
  const int lp = blockIdx.x >> 1, gbase = (blockIdx.x & 1) * 32;
  const float2* src = (const float2*)(inC + (size_t)lp * 16128);

  for (int e = tid; e < 4096; e += 256) {
    int col = e >> 7, k = e & 127;
    float2 v = make_float2(0.f, 0.f);
    if (k < 126) v = src[k * 64 + gbase + col];
    u16 hr = f2bf(v.x);
    u16 hi2 = f2bf(v.y);
    char* pr = lds + col * 528 + k * 2;
    char* pi = lds + 16896 + col * 528 + k * 2;
    *(u16*)pr = hr;        *(u16*)(pr + 256) = f2bf(v.x - bf2f(hr));
    *(u16*)pi = hi2;       *(u16*)(pi + 256) = f2bf(v.y - bf2f(hi2));
  }
  __syncthreads();

  f32x4 aRc[2][2], aRs[2][2], aIc[2][2], aIs[2][2];
#pragma unroll
  for (int a = 0; a < 2; ++a)
#pragma unroll
    for (int c = 0; c < 2; ++c) {
      f32x4 z = {0.f, 0.f, 0.f, 0.f};
      aRc[a][c] = z; aRs[a][c] = z; aIc[a][c] = z; aIs[a][c] = z;
    }

#pragma unroll
  for (int cc = 0; cc < 128; cc += 32) {
    bf16x8 brh[2], brl[2], bih[2], bil[2];
#pragma unroll
    for (int cf = 0; cf < 2; ++cf) {
      const char* pr = lds + (cf * 16 + l15) * 528 + cc * 2 + l4 * 16;
      brh[cf] = *(const bf16x8*)pr;
      brl[cf] = *(const bf16x8*)(pr + 256);
      const char* pi = lds + 16896 + (cf * 16 + l15) * 528 + cc * 2 + l4 * 16;
      bih[cf] = *(const bf16x8*)pi;
      bil[cf] = *(const bf16x8*)(pi + 256);
    }
#pragma unroll
    for (int chf = 0; chf < 2; ++chf) {
      const int ao = (wv * 32 + chf * 16 + l15) * 128 + cc + l4 * 8;
      bf16x8 ach = *(const bf16x8*)(tch + ao);
      bf16x8 acl = *(const bf16x8*)(tcl + ao);
      bf16x8 ash = *(const bf16x8*)(tsh + ao);
      bf16x8 asl = *(const bf16x8*)(tsl + ao);
#pragma unroll
      for (int cf = 0; cf < 2; ++cf) {
        aRc[chf][cf] = __builtin_amdgcn_mfma_f32_16x16x32_bf16(ach, brh[cf], aRc[chf][cf], 0, 0, 0);
        aRc[chf][cf] = __builtin_amdgcn_mfma_f32_16x16x32_bf16(ach, brl[cf], aRc[chf][cf], 0, 0, 0);
        aRc[chf][cf] = __builtin_amdgcn_mfma_f32_16x16x32_bf16(acl, brh[cf], aRc[chf][cf], 0, 0, 0);
        aRs[chf][cf] = __builtin_amdgcn_mfma_f32_16x16x32_bf16(ash, bih[cf], aRs[chf][cf], 0, 0, 0);
        aRs[chf][cf] = __builtin_amdgcn_mfma_f32_16x16x32_bf16(ash, bil[cf], aRs[chf][cf], 0, 0, 0);
        aRs[chf][cf] = __builtin_amdgcn_mfma_f32_16x16x32_bf16(asl, bih[cf], aRs[chf][cf], 0, 0, 0);
        aIc[chf][cf] = __builtin_amdgcn_mfma_f32_16x16x32_bf16(ach, bih[cf], aIc[chf][cf], 0, 0, 0);
        aIc[chf][cf] = __builtin_amdgcn_mfma_f32_16x16x32_bf16(ach, bil[cf], aIc[chf][cf], 0, 0, 0);
        aIc[chf][cf] = __builtin_amdgcn_mfma_f32_16x16x32_bf16(acl, bih[cf], aIc[chf][cf], 0, 0, 0);
        aIs[chf][cf] = __builtin_amdgcn_mfma_f32_16x16x32_bf16(ash, brh[cf], aIs[chf][cf], 0, 0, 0);
        aIs[chf][cf] = __builtin_amdgcn_mfma_f32_16x16x32_bf16(ash, brl[cf], aIs[chf][cf], 0, 0, 0);
        aIs[chf][cf] = __builtin_amdgcn_mfma_f32_16x16x32_bf16(asl, brh[cf], aIs[chf][cf], 0, 0, 0);
      }
    }
  }

  float2* dst = (float2*)(outC + (size_t)lp * 16128);
#pragma unroll
  for (int chf = 0; chf < 2; ++chf)
#pragma unroll
    for (int cf = 0; cf < 2; ++cf) {
      const int col = gbase + cf * 16 + l15;
      const int chb = wv * 32 + chf * 16 + l4 * 4;
#pragma unroll
      for (int j = 0; j < 4; ++j) {
        int ch = chb + j;
        if (ch >= 126) continue;
        float Cr, Ci;
        if (FWD) { Cr = aRc[chf][cf][j] + aRs[chf][cf][j]; Ci = aIc[chf][cf][j] - aIs[chf][cf][j]; }
        else     { Cr = aRc[chf][cf][j] - aRs[chf][cf][j]; Ci = aIc[chf][cf][j] + aIs[chf][cf][j]; }
        if (FWD) {
          int f1 = (ch <= 62) ? ch : ch - 126;
          int f2 = (col <= 62) ? col : col - 126;
          float sa = (f1 * f1 + f2 * f2 > 1600)
                       ? sqrtf(Cr * Cr + Ci * Ci) * (1.f / 15876.f) : 0.f;
          Cr *= sa; Ci *= sa;
        }
        dst[(size_t)ch * 64 + col] = make_float2(Cr, Ci);
      }
    }
}

__global__ __launch_bounds__(256)
void dft_rows_inv_mix_mf(const float* __restrict__ inC, const float* __restrict__ xc0,
                         const float* __restrict__ gb_w,
                         const u16* __restrict__ th, const u16* __restrict__ tl,
                         float* __restrict__ out, int planeBase)
{
  __shared__ char lds[64 * 528];
  const int tid = threadIdx.x;
  const int lane = tid & 63;
  const int wv = __builtin_amdgcn_readfirstlane(tid >> 6);
  const int l15 = lane & 15, l4 = lane >> 4;
  const int lp = blockIdx.x >> 1, rb = (blockIdx.x & 1) * 64;
  const float* src = inC + (size_t)lp * 16128;

  for (int e = tid; e < 8192; e += 256) {
    int row = e >> 7, k = e & 127;
    int gr = rb + row;
    float v = (gr < 126) ? src[(size_t)gr * 128 + k] : 0.f;
    u16 h = f2bf(v);
    char* p = lds + row * 528 + k * 2;
    *(u16*)p = h;
    *(u16*)(p + 256) = f2bf(v - bf2f(h));
  }
  __syncthreads();

  f32x4 acc[8];
#pragma unroll
  for (int nf = 0; nf < 8; ++nf) { f32x4 z = {0.f, 0.f, 0.f, 0.f}; acc[nf] = z; }
#pragma unroll
  for (int cc = 0; cc < 128; cc += 32) {
    const char* pb = lds + (wv * 16 + l15) * 528 + cc * 2 + l4 * 16;
    bf16x8 bh = *(const bf16x8*)pb;
    bf16x8 bl = *(const bf16x8*)(pb + 256);
#pragma unroll
    for (int nf = 0; nf < 8; ++nf) {
      const int ao = (nf * 16 + l15) * 128 + cc + l4 * 8;
      bf16x8 ah = *(const bf16x8*)(th + ao);
      bf16x8 al = *(const bf16x8*)(tl + ao);
      acc[nf] = __builtin_amdgcn_mfma_f32_16x16x32_bf16(ah, bh, acc[nf], 0, 0, 0);
      acc[nf] = __builtin_amdgcn_mfma_f32_16x16x32_bf16(ah, bl, acc[nf], 0, 0, 0);
      acc[nf] = __builtin_amdgcn_mfma_f32_16x16x32_bf16(al, bh, acc[nf], 0, 0, 0);
    }
  }
  const int row = rb + wv * 16 + l15;
  if (row < 126) {
    float w0 = fmaxf(gb_w[0], 0.f), w1 = fmaxf(gb_w[1], 0.f);
    float iv = 1.f / (w0 + w1 + 1e-8f);
    const float w0i = w0 * iv, w1i = w1 * iv;
    size_t base = (size_t)(planeBase + lp) * 15876 + (size_t)row * 126;
#pragma unroll
    for (int nf = 0; nf < 8; ++nf) {
      const int n20 = nf * 16 + l4 * 4;
#pragma unroll
      for (int j = 0; j < 4; ++j) {
        int n2 = n20 + j;
        if (n2 < 126)
          out[base + n2] = w0i * fabsf(acc[nf][j]) + w1i * xc0[base + n2];
      }
    }
  }
}

// -------- bilinear resize 31 -> 128, fused bf16 hi/lo NHWC split output --------
__global__ __launch_bounds__(256)
void resize_bf_k(const float* __restrict__ in, u16* __restrict__ xh, u16* __restrict__ xl)
{
  int idx = blockIdx.x * 256 + threadIdx.x;      // 8*128*128*16 = 2,097,152
  if (idx >= 2097152) return;
  int cg = idx & 15, x = (idx >> 4) & 127, y = (idx >> 11) & 127, b = idx >> 18;
  float sy = (y + 0.5f) * (31.f / 128.f) - 0.5f; sy = fminf(fmaxf(sy, 0.f), 30.f);
  float sx = (x + 0.5f) * (31.f / 128.f) - 0.5f; sx = fminf(fmaxf(sx, 0.f), 30.f);
  int y0 = (int)sy; float fy = sy - (float)y0; int y1 = min(y0 + 1, 30);
  int x0 = (int)sx; float fx = sx - (float)x0; int x1 = min(x0 + 1, 30);
  const float* base = in + (size_t)(b * 64 + cg * 4) * 961;
  ushort4 hv, lv;
#pragma unroll
  for (int k = 0; k < 4; ++k) {
    const float* ip = base + k * 961;
    float v = (1.f - fy) * ((1.f - fx) * ip[y0 * 31 + x0] + fx * ip[y0 * 31 + x1])
            + fy         * ((1.f - fx) * ip[y1 * 31 + x0] + fx * ip[y1 * 31 + x1]);
    u16 h = f2bf(v);
    ((u16*)&hv)[k] = h;
    ((u16*)&lv)[k] = f2bf(v - bf2f(h));
  }
  size_t o = (((size_t)b * 128 + y) * 128 + x) * 64 + cg * 4;
  *(ushort4*)(xh + o) = hv;
  *(ushort4*)(xl + o) = lv;
}

// ======= 1x1 conv (w_gc2) + log_softmax via MFMA (split-bf16), bf16 NHWC input =======
__global__ __launch_bounds__(256)
void pwlsm_mf(const u16* __restrict__ xh, const u16* __restrict__ xl,
              const u16* __restrict__ wh, const u16* __restrict__ wl,
              const float* __restrict__ bias, float* __restrict__ out)
{
  __shared__ char lds[17664];           // stage [64px][272B] (17408) / zs [64][69]f32 (17664)
  const int tid = threadIdx.x;
  const int lane = tid & 63;
  const int wv = __builtin_amdgcn_readfirstlane(tid >> 6);
  const int l15 = lane & 15, l4 = lane >> 4;
  const size_t px0 = (size_t)blockIdx.x * 64;

  for (int e = tid; e < 1024; e += 256) {
    int pix = e >> 4, part = e & 15;
    const u16* s = ((part < 8) ? xh : xl) + (px0 + pix) * 64 + (part & 7) * 8;
    char* d = lds + pix * 272 + ((part < 8) ? part * 16 : 128 + (part - 8) * 16);
    *(uint4*)d = *(const uint4*)s;
  }
  __syncthreads();

  f32x4 acc[4];
#pragma unroll
  for (int p = 0; p < 4; ++p) { f32x4 z = {0.f, 0.f, 0.f, 0.f}; acc[p] = z; }
  const int co16 = wv * 16;
  const u16* wa = wh + (size_t)(co16 + l15) * 64 + l4 * 8;
  const u16* wb = wl + (size_t)(co16 + l15) * 64 + l4 * 8;
#pragma unroll
  for (int cc = 0; cc < 64; cc += 32) {
    bf16x8 ah = *(const bf16x8*)(wa + cc);
    bf16x8 al = *(const bf16x8*)(wb + cc);
#pragma unroll
    for (int p = 0; p < 4; ++p) {
      const char* pb = lds + (16 * p + l15) * 272 + cc * 2 + l4 * 16;
      bf16x8 bh = *(const bf16x8*)pb;
      bf16x8 bl = *(const bf16x8*)(pb + 128);
      acc[p] = __builtin_amdgcn_mfma_f32_16x16x32_bf16(ah, bh, acc[p], 0, 0, 0);
      acc[p] = __builtin_amdgcn_mfma_f32_16x16x32_bf16(ah, bl, acc[p], 0, 0, 0);
      acc[p] = __builtin_amdgcn_mfma_f32_16x16x32_bf16(al, bh, acc[p], 0, 0, 0);
    }
  }
  float4 bv = *(const float4*)&bias[co16 + l4 * 4];
  __syncthreads();                      // all MFMA LDS reads done; reuse as zs
  float* zs = (float*)lds;
#pragma unroll
  for (int p = 0; p < 4; ++p) {
    int base = (16 * p + l15) * 69 + co16 + l4 * 4;
    zs[base + 0] = acc[p][0] + bv.x;
    zs[base + 1] = acc[p][1] + bv.y;
    zs[base + 2] = acc[p][2] + bv.z;
    zs[base + 3] = acc[p][3] + bv.w;
  }
  __syncthreads();
  if (tid < 64) {
    const float* z = zs + tid * 69;
    float m = -1e30f;
    for (int co = 0; co < 64; ++co) m = fmaxf(m, z[co]);
    float sum = 0.f;
    for (int co = 0; co < 64; ++co) sum += __expf(z[co] - m);
    float lse = m + __logf(sum);
    size_t g = px0 + tid;
    int b = (int)(g >> 14), px = (int)(g & 16383);
    float* op = out + ((size_t)b << 20) + px;
    for (int co = 0; co < 64; ++co) op[(size_t)co << 14] = z[co] - lse;
  }
}

// ======= final 1x1 conv (w_pw) via MFMA (split-bf16), fp32 NCHW input/output =======
__global__ __launch_bounds__(256)
void pw_mf(const float* __restrict__ in, const u16* __restrict__ wh,
           const u16* __restrict__ wl, float* __restrict__ out)
{
  __shared__ char lds[17408];           // stage [64px][272B] bf16 hi/lo
  const int tid = threadIdx.x;
  const int lane = tid & 63;
  const int wv = __builtin_amdgcn_readfirstlane(tid >> 6);
  const int l15 = lane & 15, l4 = lane >> 4;
  const size_t px0 = (size_t)blockIdx.x * 64;
  const int b = (int)(px0 >> 14), pxb = (int)(px0 & 16383);
  const float* ip = in + ((size_t)b << 20) + pxb;

  for (int e = tid; e < 4096; e += 256) {
    int cin = e >> 6, pix = e & 63;
    float v = ip[((size_t)cin << 14) + pix];
    u16 h = f2bf(v);
    *(u16*)(lds + pix * 272 + cin * 2)       = h;
    *(u16*)(lds + pix * 272 + 128 + cin * 2) = f2bf(v - bf2f(h));
  }
  __syncthreads();

  f32x4 acc[4];
#pragma unroll
  for (int p = 0; p < 4; ++p) { f32x4 z = {0.f, 0.f, 0.f, 0.f}; acc[p] = z; }
  const int co16 = wv * 16;
  const u16* wa = wh + (size_t)(co16 + l15) * 64 + l4 * 8;
  const u16* wb = wl + (size_t)(co16 + l15) * 64 + l4 * 8;
#pragma unroll
  for (int cc = 0; cc < 64; cc += 32) {
    bf16x8 ah = *(const bf16x8*)(wa + cc);
    bf16x8 al = *(const bf16x8*)(wb + cc);
#pragma unroll
    for (int p = 0; p < 4; ++p) {
      const char* pb = lds + (16 * p + l15) * 272 + cc * 2 + l4 * 16;
      bf16x8 bh = *(const bf16x8*)pb;
      bf16x8 bl = *(const bf16x8*)(pb + 128);
      acc[p] = __builtin_amdgcn_mfma_f32_16x16x32_bf16(ah, bh, acc[p], 0, 0, 0);
      acc[p] = __builtin_amdgcn_mfma_f32_16x16x32_bf16(ah, bl, acc[p], 0, 0, 0);
      acc[p] = __builtin_amdgcn_mfma_f32_16x16x32_bf16(al, bh, acc[p], 0, 0, 0);
    }
  }
  float* op = out + ((size_t)b << 20) + pxb;
#pragma unroll
  for (int p = 0; p < 4; ++p) {
    const int pix = 16 * p + l15;
    const int co = co16 + l4 * 4;
#pragma unroll
    for (int j = 0; j < 4; ++j)
      op[((size_t)(co + j) << 14) + pix] = acc[p][j];
  }
}

// ============ windowed attention: MFMA QKV (split-bf16) + register softmax ============
__global__ __launch_bounds__(256)
void attn_mf_k(const float* __restrict__ x, const u16* __restrict__ wqh,
               const u16* __restrict__ wql, const float* __restrict__ rpbt,
               float* __restrict__ o_out)
{
  __shared__ uint4 lds4[3200];          // 51200 B
  char* lds = (char*)lds4;
  const int tid = threadIdx.x;
  const int lane = tid & 63;
  const int wv = __builtin_amdgcn_readfirstlane(tid >> 6);
  const int b = blockIdx.x >> 8, gy = (blockIdx.x >> 4) & 15, gx = blockIdx.x & 15;
  const int y0 = gy * 8, x0 = gx * 8;
  const int l15 = lane & 15, l4 = lane >> 4;

  for (int e = tid; e < 4096; e += 256) {
    int cin = e >> 6, pix = e & 63;
    float v = x[((size_t)(b * 64 + cin) * 128 + (y0 + (pix >> 3))) * 128 + x0 + (pix & 7)];
    u16 h = f2bf(v);
    *(u16*)(lds + pix * 272 + cin * 2)       = h;
    *(u16*)(lds + pix * 272 + 128 + cin * 2) = f2bf(v - bf2f(h));
  }
  __syncthreads();

  f32x4 acc[3][4];
#pragma unroll
  for (int r = 0; r < 3; ++r)
#pragma unroll
    for (int p = 0; p < 4; ++p) { f32x4 z = {0.f, 0.f, 0.f, 0.f}; acc[r][p] = z; }
  const u16* wa = wqh + (size_t)(48 * wv + l15) * 64 + l4 * 8;
  const u16* wb = wql + (size_t)(48 * wv + l15) * 64 + l4 * 8;
#pragma unroll
  for (int cc = 0; cc < 64; cc += 32) {
    bf16x8 bh[4], bl[4];
#pragma unroll
    for (int p = 0; p < 4; ++p) {
      const char* pb = lds + (16 * p + l15) * 272 + cc * 2 + l4 * 16;
      bh[p] = *(const bf16x8*)pb;
      bl[p] = *(const bf16x8*)(pb + 128);
    }
#pragma unroll
    for (int r = 0; r < 3; ++r) {
      bf16x8 ah = *(const bf16x8*)(wa + r * 1024 + cc);
      bf16x8 al = *(const bf16x8*)(wb + r * 1024 + cc);
#pragma unroll
      for (int p = 0; p < 4; ++p) {
        acc[r][p] = __builtin_amdgcn_mfma_f32_16x16x32_bf16(ah, bh[p], acc[r][p], 0, 0, 0);
        acc[r][p] = __builtin_amdgcn_mfma_f32_16x16x32_bf16(ah, bl[p], acc[r][p], 0, 0, 0);
        acc[r][p] = __builtin_amdgcn_mfma_f32_16x16x32_bf16(al, bh[p], acc[r][p], 0, 0, 0);
      }
    }
  }
  __syncthreads();   // xt dead; safe to overwrite region A with Qs

#pragma unroll
  for (int r = 0; r < 3; ++r) {
    const int ch0 = 48 * wv + 16 * r + l4 * 4;
#pragma unroll
    for (int p = 0; p < 4; ++p) {
      const int pix = 16 * p + l15;
      if (ch0 < 64) {            // Q: Qs[ch][pix], pitch 65
#pragma unroll
        for (int j = 0; j < 4; ++j)
          *(float*)(lds + ((ch0 + j) * 65 + pix) * 4) = acc[r][p][j];
      } else {                   // K/V: KVT[pix][col], pitch 132
        const int col = (ch0 < 128) ? (ch0 - 64) : (64 + ch0 - 128);
        *(f32x4*)(lds + 17408 + pix * 528 + col * 4) = acc[r][p];
      }
    }
  }
  __syncthreads();

  const int row = y0 + (lane >> 3), col = x0 + (lane & 7);
  const int h0 = wv, h1 = wv + 4;
  float q0[8], q1[8];
#pragma unroll
  for (int d = 0; d < 8; ++d) {
    q0[d] = *(const float*)(lds + ((h0 * 8 + d) * 65 + lane) * 4);
    q1[d] = *(const float*)(lds + ((h1 * 8 + d) * 65 + lane) * 4);
  }
  const float* rb0 = rpbt + h0 * 4096;
  const float* rb1 = rpbt + h1 * 4096;
  float P0[64], P1[64];
#pragma unroll
  for (int j = 0; j < 64; ++j) { P0[j] = rb0[j * 64 + lane]; P1[j] = rb1[j * 64 + lane]; }
  float m0 = -1e30f, m1 = -1e30f;
#pragma unroll
  for (int j = 0; j < 64; ++j) {
    const char* kp = lds + 17408 + j * 528;
    float4 a0 = *(const float4*)(kp + (h0 * 8) * 4);
    float4 a1 = *(const float4*)(kp + (h0 * 8) * 4 + 16);
    float4 b0 = *(const float4*)(kp + (h1 * 8) * 4);
    float4 b1 = *(const float4*)(kp + (h1 * 8) * 4 + 16);
    float s0 = q0[0] * a0.x + q0[1] * a0.y + q0[2] * a0.z + q0[3] * a0.w
             + q0[4] * a1.x + q0[5] * a1.y + q0[6] * a1.z + q0[7] * a1.w;
    float s1 = q1[0] * b0.x + q1[1] * b0.y + q1[2] * b0.z + q1[3] * b0.w
             + q1[4] * b1.x + q1[5] * b1.y + q1[6] * b1.z + q1[7] * b1.w;
    s0 = s0 * ATT_SCALE + P0[j];
    s1 = s1 * ATT_SCALE + P1[j];
    P0[j] = s0; P1[j] = s1;
    m0 = fmaxf(m0, s0); m1 = fmaxf(m1, s1);
  }
  float sum0 = 0.f, sum1 = 0.f;
#pragma unroll
  for (int j = 0; j < 64; ++j) {
    float p0 = __expf(P0[j] - m0); P0[j] = p0; sum0 += p0;
    float p1 = __expf(P1[j] - m1); P1[j] = p1; sum1 += p1;
  }
  float inv0 = 1.f / sum0, inv1 = 1.f / sum1;

  float acc0[8], acc1[8];
#pragma unroll
  for (int d = 0; d < 8; ++d) { acc0[d] = 0.f; acc1[d] = 0.f; }
#pragma unroll
  for (int j = 0; j < 64; ++j) {
    const char* vp = lds + 17408 + j * 528 + 256;   // V cols start at 64 floats
    float p0 = P0[j], p1 = P1[j];
    float4 v00 = *(const float4*)(vp + (h0 * 8) * 4);
    float4 v01 = *(const float4*)(vp + (h0 * 8) * 4 + 16);
    float4 v10 = *(const float4*)(vp + (h1 * 8) * 4);
    float4 v11 = *(const float4*)(vp + (h1 * 8) * 4 + 16);
    acc0[0] += p0 * v00.x; acc0[1] += p0 * v00.y; acc0[2] += p0 * v00.z; acc0[3] += p0 * v00.w;
    acc0[4] += p0 * v01.x; acc0[5] += p0 * v01.y; acc0[6] += p0 * v01.z; acc0[7] += p0 * v01.w;
    acc1[0] += p1 * v10.x; acc1[1] += p1 * v10.y; acc1[2] += p1 * v10.z; acc1[3] += p1 * v10.w;
    acc1[4] += p1 * v11.x; acc1[5] += p1 * v11.y; acc1[6] += p1 * v11.z; acc1[7] += p1 * v11.w;
  }
#pragma unroll
  for (int d = 0; d < 8; ++d) {
    o_out[((size_t)(b * 64 + h0 * 8 + d) * 128 + row) * 128 + col] = acc0[d] * inv0;
    o_out[((size_t)(b * 64 + h1 * 8 + d) * 128 + row) * 128 + col] = acc1[d] * inv1;
  }
}

// ------- directional avg pools + add local, LDS-tiled separable version -------
__global__ __launch_bounds__(256)
void avgadd_k(const float* __restrict__ o, const float* __restrict__ loc, float* __restrict__ out)
{
  __shared__ float t[24][128];
  const int tid = threadIdx.x;
  const int y0 = blockIdx.x * 16;
  const size_t p = blockIdx.y;
  const float* op = o + (p << 14);
  for (int e = tid; e < 24 * 128; e += 256) {
    int rr = e >> 7, x = e & 127;
    int r = y0 - 3 + rr;
    float v = 0.f;
    if (r >= 0 && r <= 128) { int r2 = (r == 128) ? 126 : r; v = op[r2 * 128 + x]; }
    t[rr][x] = v;
  }
  __syncthreads();
#pragma unroll
  for (int k = 0; k < 8; ++k) {
    int idx = k * 256 + tid;
    int ly = idx >> 7, x = idx & 127;
    float s1 = 0.f;
#pragma unroll
    for (int tt = 0; tt < 8; ++tt) s1 += t[ly + tt][x];
    float s2 = 0.f;
#pragma unroll
    for (int tt = 0; tt < 8; ++tt) {
      int cc = x - 3 + tt;
      if (cc >= 0 && cc <= 128) { int ss = (cc == 128) ? 126 : cc; s2 += t[ly + 3][ss]; }
    }
    size_t gi = (p << 14) + (size_t)(y0 + ly) * 128 + x;
    out[gi] = 0.125f * (s1 + s2) + loc[gi];
  }
}

// ---------------- depthwise 8x8 conv (pad_out + pad3, zero) + BN ----------------
__global__ __launch_bounds__(256)
void dw_k(const float* __restrict__ in, const float* __restrict__ w,
          const float* __restrict__ g, const float* __restrict__ bb, float* __restrict__ out)
{
  __shared__ float t[23 * 23];
  const int tid = threadIdx.x;
  const int tx = tid & 15, ty = tid >> 4;
  const int x0 = blockIdx.x * 16, y0 = blockIdx.y * 16;
  const int pc = blockIdx.z;
  const int c = pc & 63;
  const float* ip = in + (size_t)pc * 16384;
  for (int e = tid; e < 529; e += 256) {
    int yy = e / 23, xx = e % 23;
    int iy = y0 + yy - 3, ix = x0 + xx - 3;
    t[e] = (iy >= 0 && iy < 128 && ix >= 0 && ix < 128) ? ip[iy * 128 + ix] : 0.f;
  }
  __syncthreads();
  const float* wk = w + c * 64;
  float s = 0.f;
#pragma unroll
  for (int ky = 0; ky < 8; ++ky)
#pragma unroll
    for (int kx = 0; kx < 8; ++kx)
      s += t[(ty + ky) * 23 + tx + kx] * wk[ky * 8 + kx];
  out[(size_t)pc * 16384 + (y0 + ty) * 128 + x0 + tx] = s * (g[c] * BN_SC) + bb[c];
}

// =======================================================================
extern "C" void kernel_launch(void* const* d_in, const int* in_sizes, int n_in,
                              void* d_out, int out_size, void* d_ws, size_t ws_size,
                              hipStream_t stream)
{
  const float* x      = (const float*)d_in[0];
  const float* w_qkv  = (const float*)d_in[1];
  const float* w_l1   = (const float*)d_in[2];
  const float* g_l1   = (const float*)d_in[3];
  const float* b_l1   = (const float*)d_in[4];
  const float* w_l2   = (const float*)d_in[5];
  const float* g_l2   = (const float*)d_in[6];
  const float* b_l2   = (const float*)d_in[7];
  const float* f_cos  = (const float*)d_in[8];
  const float* f_sin  = (const float*)d_in[9];
  const float* gb_b1  = (const float*)d_in[10];
  const float* gb_b2  = (const float*)d_in[11];
  const float* gb_w   = (const float*)d_in[12];
  const float* w_post = (const float*)d_in[13];
  const float* g_post = (const float*)d_in[14];
  const float* b_post = (const float*)d_in[15];
  const float* w_gc   = (const float*)d_in[16];
  const float* b_gc   = (const float*)d_in[17];
  const float* w_gc1  = (const float*)d_in[18];
  const float* b_gc1  = (const float*)d_in[19];
  const float* w_gc2  = (const float*)d_in[20];
  const float* b_gc2  = (const float*)d_in[21];
  const float* rpb    = (const float*)d_in[22];
  const float* w_dw   = (const float*)d_in[23];
  const float* g_proj = (const float*)d_in[24];
  const float* b_proj = (const float*)d_in[25];
  const float* w_pw   = (const float*)d_in[26];
  const int*   relidx = (const int*)d_in[27];
  float* out = (float*)d_out;

  // Workspace map (within the proven 102,238,208-byte footprint):
  //  R1   [0,        33554432)   scratch A; PH planes (5-6); XC7 bf16 (9-10); attn o (11-12)
  //  R2   [33554432, 67108864)   scratch B; XH_A/XL_A; xc2 (4-5); XC5P pooled (6-8);
  //                              local (10-12); dw out (13-14)
  //  R3.. [67108864, 100663296)  FFT C1/C2; XH_B/XL_B (original adjacency); out0 (12-13)
  //  TB   [100139008,100401152)  DFT trig tables (step 3 only)
  //  W    [100663296,100827392)  per-conv split weights + BLS (re-gen per conv)
  //  WQ   [100827392,100876544)  qkv split weights
  //  WG   [100876544,100892928)  w_gc2 split weights
  //  WP   [100892928,100909312)  w_pw split weights
  //  RPBT [102107136,102238208)
  char* ws = (char*)d_ws;
  float* R1   = (float*)(ws + 0);
  float* R2   = (float*)(ws + 33554432);
  float* R3   = (float*)(ws + 67108864);
  float* C1   = R3;
  float* C2   = (float*)(ws + 83623936);
  float* XC5P = (float*)(ws + 33554432);      // pooled 31^2 (R2 region, steps 6-8; xc2 dead)
  float* RPBT = (float*)(ws + 102107136);
  u16* XH_A = (u16*)(ws + 33554432);
  u16* XL_A = (u16*)(ws + 33554432 + 16777216);
  u16* XH_B = (u16*)(ws + 67108864);          // original: ends exactly at XL_B start
  u16* XL_B = (u16*)(ws + 83886080);
  u16* PH_H = (u16*)(ws + 0);                 // 16,257,024 B
  u16* PH_L = (u16*)(ws + 16257024);          // ends 32,514,048
  u16* XC7H = (u16*)(ws + 0);                 // 16,777,216 B (steps 9-10)
  u16* XC7L = (u16*)(ws + 16777216);          // ends 33,554,432
  u16* TB   = (u16*)(ws + 100139008);         // 262,144 B DFT tables
  u16* WH   = (u16*)(ws + 100663296);
  u16* WL   = (u16*)(ws + 100745216);
  float* BLS = (float*)(ws + 100827136);
  u16* WQH  = (u16*)(ws + 100827392);         // 24576 B
  u16* WQL  = (u16*)(ws + 100851968);         // 24576 B, ends 100876544
  u16* WGH  = (u16*)(ws + 100876544);         // 8192 B
  u16* WGL  = (u16*)(ws + 100884736);         // 8192 B, ends 100892928
  u16* WPH  = (u16*)(ws + 100892928);         // 8192 B
  u16* WPL  = (u16*)(ws + 100901120);         // 8192 B, ends 100909312

  rpbprep_k<<<128, 256, 0, stream>>>(rpb, relidx, RPBT);

  // 1. LOCAL: bn(conv1x1) + bn(conv3x3) on x -> XH_B/XL_B  [MFMA, fused bf16-split out]
  wsplit_k<<<144, 256, 0, stream>>>(w_l1, g_l1, WH, WL, 64, 9, 0, 0, 10);
  wsplit_k<<<16, 256, 0, stream>>>(w_l2, g_l2, WH, WL, 64, 1, 0, 9, 10);
  bls_k<<<1, 64, 0, stream>>>(b_l1, b_l2, BLS);
  xsplit_k<128><<<1024, 256, 0, stream>>>(x, XH_A, XL_A);
  convmf_k<M_LOCAL, 10, 128, 128, 1, true><<<dim3(64, 8), 256, 0, stream>>>(
      XH_A, XL_A, WH, WL, BLS, nullptr, nullptr, XH_B, XL_B);

  // 2. GABOR: valid conv, cos||sin + biases -> R2 (xc0, 126x126)
  wsplit_k<<<72, 256, 0, stream>>>(f_cos, nullptr, WH, WL, 32, 9, 0, 0, 9);
  wsplit_k<<<72, 256, 0, stream>>>(f_sin, nullptr, WH, WL, 32, 9, 32, 0, 9);
  convmf_k<M_GABOR, 9, 128, 126, 0, false><<<dim3(64, 8), 256, 0, stream>>>(
      XH_B, XL_B, WH, WL, gb_b1, gb_b2, R2, nullptr, nullptr);

  // 3. fft_h + fw-mix via MFMA DFT, 2 chunks of 256 planes -> R1 (xc1)
  tprep_k<<<256, 256, 0, stream>>>(TB);
  for (int chunk = 0; chunk < 2; ++chunk) {
    int pb = chunk * 256;
    dft_rows_fwd_mf<<<512, 256, 0, stream>>>(R2, C1, TB, TB + 16384, pb);
    dft_cols_mf<true><<<512, 256, 0, stream>>>(C1, C2, TB + 32768, TB + 49152,
                                               TB + 65536, TB + 81920);
    dft_cols_mf<false><<<512, 256, 0, stream>>>(C2, C1, TB + 32768, TB + 49152,
                                                TB + 65536, TB + 81920);
    dft_rows_inv_mix_mf<<<512, 256, 0, stream>>>(C1, R2, gb_w, TB + 98304, TB + 114688,
                                                 R1, pb);
  }

  // 4. relu6(bn(conv3x3 w_post)) -> R2 (xc2)
  wsplit_k<<<144, 256, 0, stream>>>(w_post, g_post, WH, WL, 64, 9, 0, 0, 9);
  xsplit_k<126><<<1008, 256, 0, stream>>>(R1, XH_B, XL_B);
  convmf_k<M_BNRELU6, 9, 126, 126, 1, false><<<dim3(64, 8), 256, 0, stream>>>(
      XH_B, XL_B, WH, WL, b_post, nullptr, R2, nullptr, nullptr);

  // 5. fused maxpool(2x2 s1) + stride-2 polyphase split -> PH planes (R1 region)
  mpsplit_k<<<1008, 256, 0, stream>>>(R2, PH_H, PH_L);

  // 6. MFMA stride-2 conv w_gc + relu + fused 2x2 s2 maxpool -> XC5P (R2 start; xc2 dead)
  wsplit_gc_k<<<144, 256, 0, stream>>>(w_gc, WH, WL);
  convgc_mf<<<dim3(64, 8), 256, 0, stream>>>(PH_H, PH_L, WH, WL, b_gc, XC5P);

  // 8. bilinear resize 31 -> 128 + fused bf16 split -> XH_B/XL_B   [XC5P dead after]
  resize_bf_k<<<8192, 256, 0, stream>>>(XC5P, XH_B, XL_B);

  // qkv + w_gc2 + w_pw weight splits
  wsplit_k<<<48, 256, 0, stream>>>(w_qkv, nullptr, WQH, WQL, 192, 1, 0, 0, 1);
  wsplit_k<<<16, 256, 0, stream>>>(w_gc2, nullptr, WGH, WGL, 64, 1, 0, 0, 1);
  wsplit_k<<<16, 256, 0, stream>>>(w_pw, nullptr, WPH, WPL, 64, 1, 0, 0, 1);

  // 9. relu(conv3x3 w_gc1 + b) -> XC7 bf16 NHWC (R1 region)  [fused split + relu out]
  wsplit_k<<<144, 256, 0, stream>>>(w_gc1, nullptr, WH, WL, 64, 9, 0, 0, 9);
  convmf_k<M_BIASRELU, 9, 128, 128, 1, true><<<dim3(64, 8), 256, 0, stream>>>(
      XH_B, XL_B, WH, WL, b_gc1, nullptr, nullptr, XC7H, XC7L);

  // 10. 1x1 conv w_gc2 + log_softmax -> R2 (local)   [MFMA; XC5P dead]
  pwlsm_mf<<<2048, 256, 0, stream>>>(XC7H, XC7L, WGH, WGL, b_gc2, R2);
  // 11. window attention -> R1 (o)   [XC7 dead]
  attn_mf_k<<<2048, 256, 0, stream>>>(x, WQH, WQL, RPBT, R1);
  // 12. ox + oy + local -> R3 (out0)   [LDS-tiled separable]
  avgadd_k<<<dim3(8, 512), 256, 0, stream>>>(R1, R2, R3);
  // 13. depthwise 8x8 + bn -> R2
  dw_k<<<dim3(8, 8, 512), 256, 0, stream>>>(R3, w_dw, g_proj, b_proj, R2);
  // 14. 1x1 conv w_pw -> d_out   [MFMA]
  pw_mf<<<2048, 256, 0, stream>>>(R2, WPH, WPL, out);
  (void)in_sizes; (void)n_in; (void)out_size; (void)ws_size;
}